// Round 12
// baseline (567.517 us; speedup 1.0000x reference)
//
#include <hip/hip_runtime.h>
#include <stdint.h>

#define NATOMS 200000
#define NBONDS 300000
#define NEDGE  600000
#define NSEG   (NATOMS + NBONDS)   // 500000
#define DF     128
#define EPS    1e-5f
#define SCHUNK 2048
#define NSBLK  ((NSEG + SCHUNK - 1) / SCHUNK)  // 245
#define NBUCK  32
#define NCHA   (NATOMS / 64)            // 3125 exact
#define NCHB   ((NBONDS + 63) / 64)     // 4688 (tail 32 rows = 2 full 16-row groups)
#define NCH    (NCHA + NCHB)            // 7813

typedef __attribute__((ext_vector_type(8))) short bf16x8;
typedef __attribute__((ext_vector_type(4))) float f32x4;
typedef unsigned short u16;

__device__ __forceinline__ short f2b(float f) {
  union { float f; uint32_t u; } v; v.f = f;
  uint32_t r = v.u + 0x7fffu + ((v.u >> 16) & 1u);
  return (short)(r >> 16);
}
__device__ __forceinline__ float bf2f(u16 h) {
  union { uint32_t u; float f; } v; v.u = ((uint32_t)h) << 16; return v.f;
}
__device__ __forceinline__ bf16x8 pack8(float4 u, float4 v) {
  bf16x8 t;
  t[0] = f2b(u.x); t[1] = f2b(u.y); t[2] = f2b(u.z); t[3] = f2b(u.w);
  t[4] = f2b(v.x); t[5] = f2b(v.y); t[6] = f2b(v.z); t[7] = f2b(v.w);
  return t;
}

// ---- weights -> bf16 (fallback tier only; xt tier folds this into k_setup) ----
__global__ void k_prep(const float* __restrict__ W, const float* __restrict__ Wr,
                       u16* __restrict__ Wb, u16* __restrict__ Wrb) {
  int i = blockIdx.x * blockDim.x + threadIdx.x;
  if (i < DF * DF) {
    Wb[i]  = (u16)f2b(W[i]);
    Wrb[i] = (u16)f2b(Wr[i]);
  }
}

// ---- fused setup: conv x->xT (0..4095) + hist (4096..4607) + weights (4608..4671) ----
__global__ void k_setup(const float* __restrict__ xa, const float* __restrict__ xb,
                        u16* __restrict__ xaT, u16* __restrict__ xbT,
                        const int* __restrict__ ab, const int* __restrict__ ba,
                        int* __restrict__ cnt,
                        const float* __restrict__ W, const float* __restrict__ Wr,
                        u16* __restrict__ Wb, u16* __restrict__ Wrb) {
  const int NA8 = NATOMS * DF / 8;   // 3,200,000
  const int NT8 = NSEG * DF / 8;     // 8,000,000
  int bid = blockIdx.x;
  if (bid < 4096) {
    int stride = 4096 * 256;
    for (int i = bid * 256 + threadIdx.x; i < NT8; i += stride) {
      const float* src; u16* dst; int j;
      if (i < NA8) { src = xa; dst = xaT; j = i; }
      else { src = xb; dst = xbT; j = i - NA8; }
      const float4 a = *(const float4*)(src + (size_t)j * 8);
      const float4 b = *(const float4*)(src + (size_t)j * 8 + 4);
      *(bf16x8*)(dst + (size_t)j * 8) = pack8(a, b);
    }
  } else if (bid < 4608) {
    int stride = 512 * 256;
    for (int e = (bid - 4096) * 256 + threadIdx.x; e < 2 * NEDGE; e += stride) {
      int g;
      if (e < NEDGE) g = NATOMS + ab[NEDGE + e];
      else           g = ba[NEDGE + (e - NEDGE)];
      atomicAdd(cnt + g, 1);
    }
  } else {
    int i = (bid - 4608) * 256 + threadIdx.x;
    if (i < DF * DF) {
      Wb[i]  = (u16)f2b(W[i]);
      Wrb[i] = (u16)f2b(Wr[i]);
    }
  }
}

// ---- plain hist (fallback tier) ----
__global__ void k_hist(const int* __restrict__ ab, const int* __restrict__ ba,
                       int* __restrict__ cnt) {
  int stride = gridDim.x * blockDim.x;
  for (int e = blockIdx.x * blockDim.x + threadIdx.x; e < 2 * NEDGE; e += stride) {
    int g;
    if (e < NEDGE) g = NATOMS + ab[NEDGE + e];
    else           g = ba[NEDGE + (e - NEDGE)];
    atomicAdd(cnt + g, 1);
  }
}

// ---- 3-phase exclusive scan ----
__global__ void k_scanA(const int* __restrict__ cnt, int* __restrict__ bsum) {
  __shared__ int wsm[4];
  int t = threadIdx.x;
  int base = blockIdx.x * SCHUNK + t * 8;
  int s = 0;
#pragma unroll
  for (int j = 0; j < 8; ++j) { int i = base + j; if (i < NSEG) s += cnt[i]; }
  for (int d = 1; d < 64; d <<= 1) s += __shfl_xor(s, d);
  if ((t & 63) == 0) wsm[t >> 6] = s;
  __syncthreads();
  if (t == 0) bsum[blockIdx.x] = wsm[0] + wsm[1] + wsm[2] + wsm[3];
}

__global__ void k_scanB(const int* __restrict__ bsum, int* __restrict__ bbase) {
  __shared__ int wsm[4];
  int t = threadIdx.x;
  int lane = t & 63;
  int v = (t < NSBLK) ? bsum[t] : 0;
  int s = v;
  for (int d = 1; d < 64; d <<= 1) { int n = __shfl_up(s, d); if (lane >= d) s += n; }
  if (lane == 63) wsm[t >> 6] = s;
  __syncthreads();
  int wbase = 0;
  for (int w = 0; w < (t >> 6); ++w) wbase += wsm[w];
  if (t < NSBLK) bbase[t] = wbase + s - v;
}

__global__ void k_scanC(const int* __restrict__ cnt, const int* __restrict__ bbase,
                        int* __restrict__ off, int* __restrict__ cursor) {
  __shared__ int wsm[4];
  int t = threadIdx.x;
  int lane = t & 63, wv = t >> 6;
  int base = blockIdx.x * SCHUNK + t * 8;
  int v[8]; int ts = 0;
#pragma unroll
  for (int j = 0; j < 8; ++j) { int i = base + j; v[j] = (i < NSEG) ? cnt[i] : 0; ts += v[j]; }
  int s = ts;
  for (int d = 1; d < 64; d <<= 1) { int n = __shfl_up(s, d); if (lane >= d) s += n; }
  if (lane == 63) wsm[wv] = s;
  __syncthreads();
  int wbase = bbase[blockIdx.x];
  for (int w = 0; w < wv; ++w) wbase += wsm[w];
  int run = wbase + s - ts;
#pragma unroll
  for (int j = 0; j < 8; ++j) {
    int i = base + j;
    if (i < NSEG) { off[i] = run; cursor[i] = run; }
    run += v[j];
  }
}

// ---- bucket src indices per dst ----
__global__ void k_fill(const int* __restrict__ ab, const int* __restrict__ ba,
                       int* __restrict__ cursor, int* __restrict__ sorted) {
  int stride = gridDim.x * blockDim.x;
  for (int e = blockIdx.x * blockDim.x + threadIdx.x; e < 2 * NEDGE; e += stride) {
    int g, src;
    if (e < NEDGE) { g = NATOMS + ab[NEDGE + e]; src = ab[e]; }
    else { int e2 = e - NEDGE; g = ba[NEDGE + e2]; src = ba[e2]; }
    int pos = atomicAdd(cursor + g, 1);
    sorted[pos] = src;
  }
}

// Phase B body: MFMA for chunk (TY,NR,GO,BA) reading agg tile BUF, x from XS.
#define PHASE_B(TY, NR, GO, BA, XS, BUF) {                                          \
  _Pragma("unroll")                                                                 \
  for (int rg = 0; rg < 4; ++rg) {                                                  \
    int rowbase = (BA) + rg * 16;                                                   \
    if (rowbase < (NR)) {                                                           \
      int lrow = rg * 16 + r16;                                                     \
      int sx = r16 & 7;                                                             \
      bf16x8 fA0 = *(const bf16x8*)((BUF) + lrow * DF + (((0  + kq) ^ sx) * 8));    \
      bf16x8 fA1 = *(const bf16x8*)((BUF) + lrow * DF + (((4  + kq) ^ sx) * 8));    \
      bf16x8 fA2 = *(const bf16x8*)((BUF) + lrow * DF + (((8  + kq) ^ sx) * 8));    \
      bf16x8 fA3 = *(const bf16x8*)((BUF) + lrow * DF + (((12 + kq) ^ sx) * 8));    \
      const u16* xp_ = (XS) + (size_t)(rowbase + r16) * DF + kq * 8;                \
      bf16x8 fX0 = *(const bf16x8*)(xp_);                                           \
      bf16x8 fX1 = *(const bf16x8*)(xp_ + 32);                                      \
      bf16x8 fX2 = *(const bf16x8*)(xp_ + 64);                                      \
      bf16x8 fX3 = *(const bf16x8*)(xp_ + 96);                                      \
      f32x4 bw0 = {0.f,0.f,0.f,0.f}, bw1 = {0.f,0.f,0.f,0.f};                       \
      f32x4 bre0 = {0.f,0.f,0.f,0.f}, bre1 = {0.f,0.f,0.f,0.f};                     \
      bw0 = __builtin_amdgcn_mfma_f32_16x16x32_bf16(fA0, wf[0][0], bw0, 0,0,0);     \
      bw1 = __builtin_amdgcn_mfma_f32_16x16x32_bf16(fA0, wf[1][0], bw1, 0,0,0);     \
      bre0 = __builtin_amdgcn_mfma_f32_16x16x32_bf16(fX0, wrf[0][0], bre0, 0,0,0);  \
      bre1 = __builtin_amdgcn_mfma_f32_16x16x32_bf16(fX0, wrf[1][0], bre1, 0,0,0);  \
      bw0 = __builtin_amdgcn_mfma_f32_16x16x32_bf16(fA1, wf[0][1], bw0, 0,0,0);     \
      bw1 = __builtin_amdgcn_mfma_f32_16x16x32_bf16(fA1, wf[1][1], bw1, 0,0,0);     \
      bre0 = __builtin_amdgcn_mfma_f32_16x16x32_bf16(fX1, wrf[0][1], bre0, 0,0,0);  \
      bre1 = __builtin_amdgcn_mfma_f32_16x16x32_bf16(fX1, wrf[1][1], bre1, 0,0,0);  \
      bw0 = __builtin_amdgcn_mfma_f32_16x16x32_bf16(fA2, wf[0][2], bw0, 0,0,0);     \
      bw1 = __builtin_amdgcn_mfma_f32_16x16x32_bf16(fA2, wf[1][2], bw1, 0,0,0);     \
      bre0 = __builtin_amdgcn_mfma_f32_16x16x32_bf16(fX2, wrf[0][2], bre0, 0,0,0);  \
      bre1 = __builtin_amdgcn_mfma_f32_16x16x32_bf16(fX2, wrf[1][2], bre1, 0,0,0);  \
      bw0 = __builtin_amdgcn_mfma_f32_16x16x32_bf16(fA3, wf[0][3], bw0, 0,0,0);     \
      bw1 = __builtin_amdgcn_mfma_f32_16x16x32_bf16(fA3, wf[1][3], bw1, 0,0,0);     \
      bre0 = __builtin_amdgcn_mfma_f32_16x16x32_bf16(fX3, wrf[0][3], bre0, 0,0,0);  \
      bre1 = __builtin_amdgcn_mfma_f32_16x16x32_bf16(fX3, wrf[1][3], bre1, 0,0,0);  \
      float cf0 = (float)cnt[(GO) + rowbase + kq * 4 + 0];                          \
      float cf1 = (float)cnt[(GO) + rowbase + kq * 4 + 1];                          \
      float cf2 = (float)cnt[(GO) + rowbase + kq * 4 + 2];                          \
      float cf3 = (float)cnt[(GO) + rowbase + kq * 4 + 3];                          \
      u16* gp = gT + ((size_t)((GO) + rowbase + kq * 4) << 7) + t016 + r16;         \
      float g0, g1, g2, g3, ss, qq;                                                 \
      g0 = bw0[0] + cf0 * bvv0 + fmaxf(bre0[0] + brr0, 0.f);                        \
      g1 = bw0[1] + cf1 * bvv0 + fmaxf(bre0[1] + brr0, 0.f);                        \
      g2 = bw0[2] + cf2 * bvv0 + fmaxf(bre0[2] + brr0, 0.f);                        \
      g3 = bw0[3] + cf3 * bvv0 + fmaxf(bre0[3] + brr0, 0.f);                        \
      gp[0]   = (u16)f2b(g0); gp[128] = (u16)f2b(g1);                               \
      gp[256] = (u16)f2b(g2); gp[384] = (u16)f2b(g3);                               \
      ss = g0 + g1 + g2 + g3;                                                       \
      qq = g0*g0 + g1*g1 + g2*g2 + g3*g3;                                           \
      if (TY) { sB0 += ss; qB0 += qq; } else { sA0 += ss; qA0 += qq; }              \
      g0 = bw1[0] + cf0 * bvv1 + fmaxf(bre1[0] + brr1, 0.f);                        \
      g1 = bw1[1] + cf1 * bvv1 + fmaxf(bre1[1] + brr1, 0.f);                        \
      g2 = bw1[2] + cf2 * bvv1 + fmaxf(bre1[2] + brr1, 0.f);                        \
      g3 = bw1[3] + cf3 * bvv1 + fmaxf(bre1[3] + brr1, 0.f);                        \
      gp[16]  = (u16)f2b(g0); gp[144] = (u16)f2b(g1);                               \
      gp[272] = (u16)f2b(g2); gp[400] = (u16)f2b(g3);                               \
      ss = g0 + g1 + g2 + g3;                                                       \
      qq = g0*g0 + g1*g1 + g2*g2 + g3*g3;                                           \
      if (TY) { sB1 += ss; qB1 += qq; } else { sA1 += ss; qA1 += qq; }              \
    }                                                                               \
  }                                                                                 \
}

// ==== fused gather + GEMM: dbuf LDS, 1 barrier/chunk, idx-prefetch Phase A ====
__global__ __launch_bounds__(256) void k_fuse(
    const u16* __restrict__ xaT, const u16* __restrict__ xbT,
    const int* __restrict__ sorted, const int* __restrict__ off,
    const int* __restrict__ cnt, u16* __restrict__ gT,
    const u16* __restrict__ Wb, const u16* __restrict__ Wrb,
    const float* __restrict__ bb, const float* __restrict__ brb,
    float* __restrict__ stats) {
  __shared__ u16 aggL[2][64 * DF];   // 2 x 16 KB, swizzled at 16B-chunk granularity

  int tid = threadIdx.x;
  int lane = tid & 63;
  int wv = tid >> 6;            // wave 0..3 -> feature strip (Phase B)
  int r16 = lane & 15, kq = lane >> 4;
  int t016 = wv * 32;
  int qw = tid >> 4;            // quarter-wave 0..15
  int l16 = tid & 15;

  // weights resident in registers (64 VGPRs)
  bf16x8 wf[2][4], wrf[2][4];
#pragma unroll
  for (int ti = 0; ti < 2; ++ti) {
#pragma unroll
    for (int kk = 0; kk < 4; ++kk) {
      size_t o = (size_t)(t016 + ti * 16 + r16) * DF + kk * 32 + kq * 8;
      wf[ti][kk]  = *(const bf16x8*)(Wb + o);
      wrf[ti][kk] = *(const bf16x8*)(Wrb + o);
    }
  }
  float bvv0 = bb[t016 + r16],      brr0 = brb[t016 + r16];
  float bvv1 = bb[t016 + 16 + r16], brr1 = brb[t016 + 16 + r16];

  float sA0 = 0.f, sA1 = 0.f, qA0 = 0.f, qA1 = 0.f;
  float sB0 = 0.f, sB1 = 0.f, qB0 = 0.f, qB1 = 0.f;

  int pb = 0;
  int pTyp = 0, pNrows = 0, pGoff = 0, pBase = 0;
  const u16* pXsrc = xaT;
  bool hasPrev = false;

  for (int c = blockIdx.x; c < NCH; c += gridDim.x) {
    int typ, nrows, goff, base;
    if (c < NCHA) { typ = 0; nrows = NATOMS; goff = 0; base = c * 64; }
    else { typ = 1; nrows = NBONDS; goff = NATOMS; base = (c - NCHA) * 64; }
    const u16* gsrc = typ ? xaT : xbT;   // bond dst <- atom srcs; atom dst <- bond srcs
    const u16* xsrc = typ ? xbT : xaT;

    // ---- Phase A: idx-prefetch gather into aggL[pb] ----
    // Quarter-wave owns 4 rows, processed as 2 halves of 2 rows.
    // Per half: prefetch up to 8 idx/row to REGISTERS (all independent),
    // then up to 16 fully-independent row loads. Rare deg>8 slow path.
    {
      const u16* gp16 = gsrc + l16 * 8;
      u16* bufp = aggL[pb];
      int swz = (l16 ^ (qw & 7)) * 8;   // rows qw+16m share (row&7) == qw&7
#pragma unroll
      for (int half = 0; half < 2; ++half) {
        int vr0 = base + qw + 32 * half;
        int vr1 = vr0 + 16;
        int s0 = 0, s1 = 0, d0 = 0, d1 = 0;
        if (vr0 < nrows) { s0 = off[goff + vr0]; d0 = cnt[goff + vr0]; }
        if (vr1 < nrows) { s1 = off[goff + vr1]; d1 = cnt[goff + vr1]; }
        int ix0[8], ix1[8];
#pragma unroll
        for (int k = 0; k < 8; ++k) {
          ix0[k] = (k < d0) ? sorted[s0 + k] : -1;
          ix1[k] = (k < d1) ? sorted[s1 + k] : -1;
        }
        float A0[8], A1[8];
#pragma unroll
        for (int j = 0; j < 8; ++j) { A0[j] = 0.f; A1[j] = 0.f; }
#pragma unroll
        for (int k = 0; k < 8; ++k) {
          if (ix0[k] >= 0) {
            bf16x8 v = *(const bf16x8*)(gp16 + (size_t)ix0[k] * DF);
#pragma unroll
            for (int j = 0; j < 8; ++j) A0[j] += bf2f((u16)v[j]);
          }
          if (ix1[k] >= 0) {
            bf16x8 v = *(const bf16x8*)(gp16 + (size_t)ix1[k] * DF);
#pragma unroll
            for (int j = 0; j < 8; ++j) A1[j] += bf2f((u16)v[j]);
          }
        }
        for (int k = 8; k < d0; ++k) {            // rare (P ~0.1%)
          int i0 = sorted[s0 + k];
          bf16x8 v = *(const bf16x8*)(gp16 + (size_t)i0 * DF);
#pragma unroll
          for (int j = 0; j < 8; ++j) A0[j] += bf2f((u16)v[j]);
        }
        for (int k = 8; k < d1; ++k) {
          int i1 = sorted[s1 + k];
          bf16x8 v = *(const bf16x8*)(gp16 + (size_t)i1 * DF);
#pragma unroll
          for (int j = 0; j < 8; ++j) A1[j] += bf2f((u16)v[j]);
        }
        if (vr0 < nrows) {
          bf16x8 rr;
#pragma unroll
          for (int j = 0; j < 8; ++j) rr[j] = f2b(A0[j]);
          *(bf16x8*)(bufp + (qw + 32 * half) * DF + swz) = rr;
        }
        if (vr1 < nrows) {
          bf16x8 rr;
#pragma unroll
          for (int j = 0; j < 8; ++j) rr[j] = f2b(A1[j]);
          *(bf16x8*)(bufp + (qw + 16 + 32 * half) * DF + swz) = rr;
        }
      }
    }

    // ---- Phase B for PREVIOUS chunk from the other buffer ----
    if (hasPrev) {
      PHASE_B(pTyp, pNrows, pGoff, pBase, pXsrc, aggL[pb ^ 1])
    }
    __syncthreads();   // aggL[pb] complete; aggL[pb^1] fully consumed

    pTyp = typ; pNrows = nrows; pGoff = goff; pBase = base; pXsrc = xsrc;
    hasPrev = true; pb ^= 1;
  }
  if (hasPrev) {
    PHASE_B(pTyp, pNrows, pGoff, pBase, pXsrc, aggL[pb ^ 1])
  }

  int bkt = blockIdx.x & (NBUCK - 1);
  float* p = stats + (size_t)bkt * 4 * DF;
  {
    float s0 = sA0, q0 = qA0, s1 = sB0, q1 = qB0;
    s0 += __shfl_xor(s0, 16); q0 += __shfl_xor(q0, 16);
    s1 += __shfl_xor(s1, 16); q1 += __shfl_xor(q1, 16);
    s0 += __shfl_xor(s0, 32); q0 += __shfl_xor(q0, 32);
    s1 += __shfl_xor(s1, 32); q1 += __shfl_xor(q1, 32);
    if (kq == 0) {
      int feat = t016 + r16;
      atomicAdd(p + 0 * DF + feat, s0);
      atomicAdd(p + 1 * DF + feat, q0);
      atomicAdd(p + 2 * DF + feat, s1);
      atomicAdd(p + 3 * DF + feat, q1);
    }
  }
  {
    float s0 = sA1, q0 = qA1, s1 = sB1, q1 = qB1;
    s0 += __shfl_xor(s0, 16); q0 += __shfl_xor(q0, 16);
    s1 += __shfl_xor(s1, 16); q1 += __shfl_xor(q1, 16);
    s0 += __shfl_xor(s0, 32); q0 += __shfl_xor(q0, 32);
    s1 += __shfl_xor(s1, 32); q1 += __shfl_xor(q1, 32);
    if (kq == 0) {
      int feat = t016 + 16 + r16;
      atomicAdd(p + 0 * DF + feat, s0);
      atomicAdd(p + 1 * DF + feat, q0);
      atomicAdd(p + 2 * DF + feat, s1);
      atomicAdd(p + 3 * DF + feat, q1);
    }
  }
}

// ---- fallback: gather fp32 ----
__global__ void k_gather_f(const float* __restrict__ xa, const float* __restrict__ xb,
                           const int* __restrict__ sorted, const int* __restrict__ off,
                           const int* __restrict__ cnt, float* __restrict__ outf) {
  int l32 = threadIdx.x & 31;
  int hwid = (blockIdx.x * blockDim.x + threadIdx.x) >> 5;
  int nhw = (gridDim.x * blockDim.x) >> 5;
  for (int g = hwid; g < NSEG; g += nhw) {
    int start = off[g], deg = cnt[g];
    const float* src = (g < NATOMS) ? xb : xa;
    float a0 = 0.f, a1 = 0.f, a2 = 0.f, a3 = 0.f;
    int k = 0;
    for (; k + 1 < deg; k += 2) {
      int s0 = sorted[start + k], s1 = sorted[start + k + 1];
      float4 v0 = *(const float4*)(src + (size_t)s0 * DF + l32 * 4);
      float4 v1 = *(const float4*)(src + (size_t)s1 * DF + l32 * 4);
      a0 += v0.x + v1.x; a1 += v0.y + v1.y; a2 += v0.z + v1.z; a3 += v0.w + v1.w;
    }
    if (k < deg) {
      int s0 = sorted[start + k];
      float4 v0 = *(const float4*)(src + (size_t)s0 * DF + l32 * 4);
      a0 += v0.x; a1 += v0.y; a2 += v0.z; a3 += v0.w;
    }
    float4 r; r.x = a0; r.y = a1; r.z = a2; r.w = a3;
    *(float4*)(outf + (size_t)g * DF + l32 * 4) = r;
  }
}

// ---- fallback GEMM (fp32 agg in outf, in place) ----
__global__ __launch_bounds__(256) void k_gemm0(
    const float* __restrict__ xa, const float* __restrict__ xb,
    float* __restrict__ outf, const int* __restrict__ cnt,
    const u16* __restrict__ Wb, const u16* __restrict__ Wrb,
    const float* __restrict__ bb, const float* __restrict__ brb,
    float* __restrict__ stats) {
  int lane = threadIdx.x & 63;
  int wv = threadIdx.x >> 6;
  int r16 = lane & 15, kq = lane >> 4;
  int t016 = wv * 32;

  bf16x8 wf[2][4], wrf[2][4];
#pragma unroll
  for (int ti = 0; ti < 2; ++ti) {
#pragma unroll
    for (int kk = 0; kk < 4; ++kk) {
      size_t o = (size_t)(t016 + ti * 16 + r16) * DF + kk * 32 + kq * 8;
      wf[ti][kk]  = *(const bf16x8*)(Wb + o);
      wrf[ti][kk] = *(const bf16x8*)(Wrb + o);
    }
  }
  float bvv[2] = { bb[t016 + r16], bb[t016 + 16 + r16] };
  float brr[2] = { brb[t016 + r16], brb[t016 + 16 + r16] };

  float sA[2] = {0.f, 0.f}, qA[2] = {0.f, 0.f};
  float sB[2] = {0.f, 0.f}, qB[2] = {0.f, 0.f};

  for (int c = blockIdx.x; c < NCH; c += gridDim.x) {
    int typ, nrows, goff, base;
    if (c < NCHA) { typ = 0; nrows = NATOMS; goff = 0; base = c * 64; }
    else { typ = 1; nrows = NBONDS; goff = NATOMS; base = (c - NCHA) * 64; }
    const float* xsrc = typ ? xb : xa;

#pragma unroll
    for (int rg = 0; rg < 4; ++rg) {
      int rowbase = base + rg * 16;
      if (rowbase < nrows) {
        int row = rowbase + r16;
        const float* ap = outf + (size_t)(goff + row) * DF + kq * 8;
        const float* xp = xsrc + (size_t)row * DF + kq * 8;
        bf16x8 fA[4], fX[4];
#pragma unroll
        for (int kk = 0; kk < 4; ++kk) {
          fA[kk] = pack8(*(const float4*)(ap + kk * 32), *(const float4*)(ap + kk * 32 + 4));
          fX[kk] = pack8(*(const float4*)(xp + kk * 32), *(const float4*)(xp + kk * 32 + 4));
        }
        __syncthreads();

        f32x4 accW[2], accR[2];
#pragma unroll
        for (int ti = 0; ti < 2; ++ti) {
#pragma unroll
          for (int r = 0; r < 4; ++r) { accW[ti][r] = 0.f; accR[ti][r] = 0.f; }
        }
#pragma unroll
        for (int kk = 0; kk < 4; ++kk) {
#pragma unroll
          for (int ti = 0; ti < 2; ++ti) {
            accW[ti] = __builtin_amdgcn_mfma_f32_16x16x32_bf16(fA[kk], wf[ti][kk], accW[ti], 0, 0, 0);
            accR[ti] = __builtin_amdgcn_mfma_f32_16x16x32_bf16(fX[kk], wrf[ti][kk], accR[ti], 0, 0, 0);
          }
        }
        float cf[4];
#pragma unroll
        for (int r = 0; r < 4; ++r)
          cf[r] = (float)cnt[goff + rowbase + kq * 4 + r];
#pragma unroll
        for (int ti = 0; ti < 2; ++ti) {
          int feat = t016 + ti * 16 + r16;
          float s = 0.f, q = 0.f;
#pragma unroll
          for (int r = 0; r < 4; ++r) {
            int grow = rowbase + kq * 4 + r;
            float gg = accW[ti][r] + cf[r] * bvv[ti] + fmaxf(accR[ti][r] + brr[ti], 0.f);
            outf[(size_t)(goff + grow) * DF + feat] = gg;
            s += gg; q += gg * gg;
          }
          if (typ == 0) { sA[ti] += s; qA[ti] += q; }
          else          { sB[ti] += s; qB[ti] += q; }
        }
      }
    }
  }

  int bkt = blockIdx.x & (NBUCK - 1);
  float* p = stats + (size_t)bkt * 4 * DF;
#pragma unroll
  for (int ti = 0; ti < 2; ++ti) {
    float s0 = sA[ti], q0 = qA[ti], s1 = sB[ti], q1 = qB[ti];
    s0 += __shfl_xor(s0, 16); q0 += __shfl_xor(q0, 16);
    s1 += __shfl_xor(s1, 16); q1 += __shfl_xor(q1, 16);
    s0 += __shfl_xor(s0, 32); q0 += __shfl_xor(q0, 32);
    s1 += __shfl_xor(s1, 32); q1 += __shfl_xor(q1, 32);
    if (kq == 0) {
      int feat = t016 + ti * 16 + r16;
      atomicAdd(p + 0 * DF + feat, s0);
      atomicAdd(p + 1 * DF + feat, q0);
      atomicAdd(p + 2 * DF + feat, s1);
      atomicAdd(p + 3 * DF + feat, q1);
    }
  }
}

// ---- finalize stats -> scale/shift ----
__global__ void k_stats(const float* __restrict__ stats,
                        const float* __restrict__ ga, const float* __restrict__ bea,
                        const float* __restrict__ gb, const float* __restrict__ beb,
                        float* __restrict__ scale, float* __restrict__ shift) {
  int tid = threadIdx.x;
  if (tid < 2 * DF) {
    int t = tid >> 7, f = tid & (DF - 1);
    float S = 0.f, SS = 0.f;
    for (int bk = 0; bk < NBUCK; ++bk) {
      const float* p = stats + (size_t)bk * 4 * DF;
      S  += p[(2 * t) * DF + f];
      SS += p[(2 * t + 1) * DF + f];
    }
    float n = t ? (float)NBONDS : (float)NATOMS;
    float mean = S / n;
    float var = SS / n - mean * mean;
    float rstd = rsqrtf(var + EPS);
    float g = t ? gb[f] : ga[f];
    float be = t ? beb[f] : bea[f];
    scale[tid] = rstd * g;
    shift[tid] = be - mean * rstd * g;
  }
}

// ---- normalize: TIER1 reads bf16 g, writes fp32; TIER0 in-place fp32 ----
template<int TIER>
__global__ void k_norm(float* __restrict__ out, const u16* __restrict__ gT,
                       const float* __restrict__ scale, const float* __restrict__ shift) {
  if constexpr (TIER) {
    const size_t nv = (size_t)NSEG * DF / 8;
    size_t stride = (size_t)gridDim.x * blockDim.x;
    for (size_t i = (size_t)blockIdx.x * blockDim.x + threadIdx.x; i < nv; i += stride) {
      size_t e = i * 8;
      int t = e >= (size_t)NATOMS * DF;
      int f = (int)(e & (DF - 1));
      bf16x8 v = *(const bf16x8*)(gT + e);
      const float* sc = scale + t * DF + f;
      const float* sh = shift + t * DF + f;
      float4 o0, o1;
      o0.x = fmaf(bf2f((u16)v[0]), sc[0], sh[0]);
      o0.y = fmaf(bf2f((u16)v[1]), sc[1], sh[1]);
      o0.z = fmaf(bf2f((u16)v[2]), sc[2], sh[2]);
      o0.w = fmaf(bf2f((u16)v[3]), sc[3], sh[3]);
      o1.x = fmaf(bf2f((u16)v[4]), sc[4], sh[4]);
      o1.y = fmaf(bf2f((u16)v[5]), sc[5], sh[5]);
      o1.z = fmaf(bf2f((u16)v[6]), sc[6], sh[6]);
      o1.w = fmaf(bf2f((u16)v[7]), sc[7], sh[7]);
      *(float4*)(out + e) = o0;
      *(float4*)(out + e + 4) = o1;
    }
  } else {
    const size_t nv = (size_t)NSEG * DF / 4;
    size_t stride = (size_t)gridDim.x * blockDim.x;
    for (size_t i = (size_t)blockIdx.x * blockDim.x + threadIdx.x; i < nv; i += stride) {
      size_t e = i * 4;
      int t = e >= (size_t)NATOMS * DF;
      int f = (int)(e & (DF - 1));
      const float* sc = scale + t * DF + f;
      const float* sh = shift + t * DF + f;
      float4 v = ((float4*)out)[i];
      v.x = fmaf(v.x, sc[0], sh[0]);
      v.y = fmaf(v.y, sc[1], sh[1]);
      v.z = fmaf(v.z, sc[2], sh[2]);
      v.w = fmaf(v.w, sc[3], sh[3]);
      ((float4*)out)[i] = v;
    }
  }
}

extern "C" void kernel_launch(void* const* d_in, const int* in_sizes, int n_in,
                              void* d_out, int out_size, void* d_ws, size_t ws_size,
                              hipStream_t stream) {
  const float* xa  = (const float*)d_in[0];
  const float* xb  = (const float*)d_in[1];
  const int*   ab  = (const int*)d_in[2];
  const int*   ba  = (const int*)d_in[3];
  const float* W   = (const float*)d_in[4];
  const float* b   = (const float*)d_in[5];
  const float* Wr  = (const float*)d_in[6];
  const float* br  = (const float*)d_in[7];
  const float* ga  = (const float*)d_in[8];
  const float* bea = (const float*)d_in[9];
  const float* gb  = (const float*)d_in[10];
  const float* beb = (const float*)d_in[11];
  float* out = (float*)d_out;

  char* ws = (char*)d_ws;
  int*   cnt    = (int*)ws;                       // 2,000,000
  int*   off    = (int*)(ws +  2000000);          // 2,000,000
  int*   cursor = (int*)(ws +  4000000);          // 2,000,000
  int*   sorted = (int*)(ws +  6000000);          // 4,800,000
  float* stats  = (float*)(ws + 10800000);        // 65,536
  int*   bsum   = (int*)(ws + 10865536);          // 1,024
  int*   bbase  = (int*)(ws + 10866560);          // 1,024
  u16*   Wbf    = (u16*)(ws + 10867584);          // 32,768
  u16*   Wrbf   = (u16*)(ws + 10900352);          // 32,768
  float* scale  = (float*)(ws + 10933120);        // 1,024
  float* shift  = (float*)(ws + 10934144);        // 1,024
  u16*   gT   = (u16*)(ws + 10935168);            // 128,000,000
  u16*   xaT  = (u16*)(ws + 138935168);           //  51,200,000
  u16*   xbT  = (u16*)(ws + 190135168);           //  76,800,000 -> ends 266,935,168
  const bool xt = ws_size >= 266935168ull;        // bf16 tier

  hipMemsetAsync(cnt, 0, 2000000, stream);
  hipMemsetAsync(stats, 0, 65536, stream);

  if (xt) {
    k_setup<<<4672, 256, 0, stream>>>(xa, xb, xaT, xbT, ab, ba, cnt, W, Wr, Wbf, Wrbf);
  } else {
    k_prep<<<64, 256, 0, stream>>>(W, Wr, Wbf, Wrbf);
    k_hist<<<2048, 256, 0, stream>>>(ab, ba, cnt);
  }
  k_scanA<<<NSBLK, 256, 0, stream>>>(cnt, bsum);
  k_scanB<<<1, 256, 0, stream>>>(bsum, bbase);
  k_scanC<<<NSBLK, 256, 0, stream>>>(cnt, bbase, off, cursor);
  k_fill<<<2048, 256, 0, stream>>>(ab, ba, cursor, sorted);

  if (xt) {
    k_fuse<<<2048, 256, 0, stream>>>(xaT, xbT, sorted, off, cnt, gT,
                                     Wbf, Wrbf, b, br, stats);
    k_stats<<<1, 256, 0, stream>>>(stats, ga, bea, gb, beb, scale, shift);
    k_norm<1><<<4096, 256, 0, stream>>>(out, gT, scale, shift);
  } else {
    k_gather_f<<<8192, 256, 0, stream>>>(xa, xb, sorted, off, cnt, out);
    k_gemm0<<<2048, 256, 0, stream>>>(xa, xb, out, cnt, Wbf, Wrbf, b, br, stats);
    k_stats<<<1, 256, 0, stream>>>(stats, ga, bea, gb, beb, scale, shift);
    k_norm<0><<<8192, 256, 0, stream>>>(out, gT, scale, shift);
  }
}

// Round 13
// 517.590 us; speedup vs baseline: 1.0965x; 1.0965x over previous
//
#include <hip/hip_runtime.h>
#include <stdint.h>

#define NATOMS 200000
#define NBONDS 300000
#define NEDGE  600000
#define NSEG   (NATOMS + NBONDS)   // 500000
#define DF     128
#define EPS    1e-5f
#define SCHUNK 2048
#define NSBLK  ((NSEG + SCHUNK - 1) / SCHUNK)  // 245
#define NBUCK  32
#define NCHA   (NATOMS / 64)            // 3125 exact
#define NCHB   ((NBONDS + 63) / 64)     // 4688 (tail 32 rows = 2 full 16-row groups)
#define NCH    (NCHA + NCHB)            // 7813

typedef __attribute__((ext_vector_type(8))) short bf16x8;
typedef __attribute__((ext_vector_type(4))) float f32x4;
typedef unsigned short u16;

__device__ __forceinline__ short f2b(float f) {
  union { float f; uint32_t u; } v; v.f = f;
  uint32_t r = v.u + 0x7fffu + ((v.u >> 16) & 1u);
  return (short)(r >> 16);
}
__device__ __forceinline__ float bf2f(u16 h) {
  union { uint32_t u; float f; } v; v.u = ((uint32_t)h) << 16; return v.f;
}
__device__ __forceinline__ bf16x8 pack8(float4 u, float4 v) {
  bf16x8 t;
  t[0] = f2b(u.x); t[1] = f2b(u.y); t[2] = f2b(u.z); t[3] = f2b(u.w);
  t[4] = f2b(v.x); t[5] = f2b(v.y); t[6] = f2b(v.z); t[7] = f2b(v.w);
  return t;
}

// ---- weights -> bf16 (fallback tier only; xt tier folds this into k_setup) ----
__global__ void k_prep(const float* __restrict__ W, const float* __restrict__ Wr,
                       u16* __restrict__ Wb, u16* __restrict__ Wrb) {
  int i = blockIdx.x * blockDim.x + threadIdx.x;
  if (i < DF * DF) {
    Wb[i]  = (u16)f2b(W[i]);
    Wrb[i] = (u16)f2b(Wr[i]);
  }
}

// ---- fused setup: conv x->xT (0..4095) + hist (4096..4607) + weights (4608..4671) ----
__global__ void k_setup(const float* __restrict__ xa, const float* __restrict__ xb,
                        u16* __restrict__ xaT, u16* __restrict__ xbT,
                        const int* __restrict__ ab, const int* __restrict__ ba,
                        int* __restrict__ cnt,
                        const float* __restrict__ W, const float* __restrict__ Wr,
                        u16* __restrict__ Wb, u16* __restrict__ Wrb) {
  const int NA8 = NATOMS * DF / 8;   // 3,200,000
  const int NT8 = NSEG * DF / 8;     // 8,000,000
  int bid = blockIdx.x;
  if (bid < 4096) {
    int stride = 4096 * 256;
    for (int i = bid * 256 + threadIdx.x; i < NT8; i += stride) {
      const float* src; u16* dst; int j;
      if (i < NA8) { src = xa; dst = xaT; j = i; }
      else { src = xb; dst = xbT; j = i - NA8; }
      const float4 a = *(const float4*)(src + (size_t)j * 8);
      const float4 b = *(const float4*)(src + (size_t)j * 8 + 4);
      *(bf16x8*)(dst + (size_t)j * 8) = pack8(a, b);
    }
  } else if (bid < 4608) {
    int stride = 512 * 256;
    for (int e = (bid - 4096) * 256 + threadIdx.x; e < 2 * NEDGE; e += stride) {
      int g;
      if (e < NEDGE) g = NATOMS + ab[NEDGE + e];
      else           g = ba[NEDGE + (e - NEDGE)];
      atomicAdd(cnt + g, 1);
    }
  } else {
    int i = (bid - 4608) * 256 + threadIdx.x;
    if (i < DF * DF) {
      Wb[i]  = (u16)f2b(W[i]);
      Wrb[i] = (u16)f2b(Wr[i]);
    }
  }
}

// ---- plain hist (fallback tier) ----
__global__ void k_hist(const int* __restrict__ ab, const int* __restrict__ ba,
                       int* __restrict__ cnt) {
  int stride = gridDim.x * blockDim.x;
  for (int e = blockIdx.x * blockDim.x + threadIdx.x; e < 2 * NEDGE; e += stride) {
    int g;
    if (e < NEDGE) g = NATOMS + ab[NEDGE + e];
    else           g = ba[NEDGE + (e - NEDGE)];
    atomicAdd(cnt + g, 1);
  }
}

// ---- 3-phase exclusive scan ----
__global__ void k_scanA(const int* __restrict__ cnt, int* __restrict__ bsum) {
  __shared__ int wsm[4];
  int t = threadIdx.x;
  int base = blockIdx.x * SCHUNK + t * 8;
  int s = 0;
#pragma unroll
  for (int j = 0; j < 8; ++j) { int i = base + j; if (i < NSEG) s += cnt[i]; }
  for (int d = 1; d < 64; d <<= 1) s += __shfl_xor(s, d);
  if ((t & 63) == 0) wsm[t >> 6] = s;
  __syncthreads();
  if (t == 0) bsum[blockIdx.x] = wsm[0] + wsm[1] + wsm[2] + wsm[3];
}

__global__ void k_scanB(const int* __restrict__ bsum, int* __restrict__ bbase) {
  __shared__ int wsm[4];
  int t = threadIdx.x;
  int lane = t & 63;
  int v = (t < NSBLK) ? bsum[t] : 0;
  int s = v;
  for (int d = 1; d < 64; d <<= 1) { int n = __shfl_up(s, d); if (lane >= d) s += n; }
  if (lane == 63) wsm[t >> 6] = s;
  __syncthreads();
  int wbase = 0;
  for (int w = 0; w < (t >> 6); ++w) wbase += wsm[w];
  if (t < NSBLK) bbase[t] = wbase + s - v;
}

__global__ void k_scanC(const int* __restrict__ cnt, const int* __restrict__ bbase,
                        int* __restrict__ off, int* __restrict__ cursor) {
  __shared__ int wsm[4];
  int t = threadIdx.x;
  int lane = t & 63, wv = t >> 6;
  int base = blockIdx.x * SCHUNK + t * 8;
  int v[8]; int ts = 0;
#pragma unroll
  for (int j = 0; j < 8; ++j) { int i = base + j; v[j] = (i < NSEG) ? cnt[i] : 0; ts += v[j]; }
  int s = ts;
  for (int d = 1; d < 64; d <<= 1) { int n = __shfl_up(s, d); if (lane >= d) s += n; }
  if (lane == 63) wsm[wv] = s;
  __syncthreads();
  int wbase = bbase[blockIdx.x];
  for (int w = 0; w < wv; ++w) wbase += wsm[w];
  int run = wbase + s - ts;
#pragma unroll
  for (int j = 0; j < 8; ++j) {
    int i = base + j;
    if (i < NSEG) { off[i] = run; cursor[i] = run; }
    run += v[j];
  }
}

// ---- bucket src indices per dst ----
__global__ void k_fill(const int* __restrict__ ab, const int* __restrict__ ba,
                       int* __restrict__ cursor, int* __restrict__ sorted) {
  int stride = gridDim.x * blockDim.x;
  for (int e = blockIdx.x * blockDim.x + threadIdx.x; e < 2 * NEDGE; e += stride) {
    int g, src;
    if (e < NEDGE) { g = NATOMS + ab[NEDGE + e]; src = ab[e]; }
    else { int e2 = e - NEDGE; g = ba[NEDGE + e2]; src = ba[e2]; }
    int pos = atomicAdd(cursor + g, 1);
    sorted[pos] = src;
  }
}

// Phase B body: MFMA for chunk (TY,NR,GO,BA) reading agg tile BUF, x from XS.
// gT stores are NON-TEMPORAL: keeps xT resident in L3 (gather hit-rate lever).
#define PHASE_B(TY, NR, GO, BA, XS, BUF) {                                          \
  _Pragma("unroll")                                                                 \
  for (int rg = 0; rg < 4; ++rg) {                                                  \
    int rowbase = (BA) + rg * 16;                                                   \
    if (rowbase < (NR)) {                                                           \
      int lrow = rg * 16 + r16;                                                     \
      int sx = r16 & 7;                                                             \
      bf16x8 fA0 = *(const bf16x8*)((BUF) + lrow * DF + (((0  + kq) ^ sx) * 8));    \
      bf16x8 fA1 = *(const bf16x8*)((BUF) + lrow * DF + (((4  + kq) ^ sx) * 8));    \
      bf16x8 fA2 = *(const bf16x8*)((BUF) + lrow * DF + (((8  + kq) ^ sx) * 8));    \
      bf16x8 fA3 = *(const bf16x8*)((BUF) + lrow * DF + (((12 + kq) ^ sx) * 8));    \
      const u16* xp_ = (XS) + (size_t)(rowbase + r16) * DF + kq * 8;                \
      bf16x8 fX0 = *(const bf16x8*)(xp_);                                           \
      bf16x8 fX1 = *(const bf16x8*)(xp_ + 32);                                      \
      bf16x8 fX2 = *(const bf16x8*)(xp_ + 64);                                      \
      bf16x8 fX3 = *(const bf16x8*)(xp_ + 96);                                      \
      f32x4 bw0 = {0.f,0.f,0.f,0.f}, bw1 = {0.f,0.f,0.f,0.f};                       \
      f32x4 bre0 = {0.f,0.f,0.f,0.f}, bre1 = {0.f,0.f,0.f,0.f};                     \
      bw0 = __builtin_amdgcn_mfma_f32_16x16x32_bf16(fA0, wf[0][0], bw0, 0,0,0);     \
      bw1 = __builtin_amdgcn_mfma_f32_16x16x32_bf16(fA0, wf[1][0], bw1, 0,0,0);     \
      bre0 = __builtin_amdgcn_mfma_f32_16x16x32_bf16(fX0, wrf[0][0], bre0, 0,0,0);  \
      bre1 = __builtin_amdgcn_mfma_f32_16x16x32_bf16(fX0, wrf[1][0], bre1, 0,0,0);  \
      bw0 = __builtin_amdgcn_mfma_f32_16x16x32_bf16(fA1, wf[0][1], bw0, 0,0,0);     \
      bw1 = __builtin_amdgcn_mfma_f32_16x16x32_bf16(fA1, wf[1][1], bw1, 0,0,0);     \
      bre0 = __builtin_amdgcn_mfma_f32_16x16x32_bf16(fX1, wrf[0][1], bre0, 0,0,0);  \
      bre1 = __builtin_amdgcn_mfma_f32_16x16x32_bf16(fX1, wrf[1][1], bre1, 0,0,0);  \
      bw0 = __builtin_amdgcn_mfma_f32_16x16x32_bf16(fA2, wf[0][2], bw0, 0,0,0);     \
      bw1 = __builtin_amdgcn_mfma_f32_16x16x32_bf16(fA2, wf[1][2], bw1, 0,0,0);     \
      bre0 = __builtin_amdgcn_mfma_f32_16x16x32_bf16(fX2, wrf[0][2], bre0, 0,0,0);  \
      bre1 = __builtin_amdgcn_mfma_f32_16x16x32_bf16(fX2, wrf[1][2], bre1, 0,0,0);  \
      bw0 = __builtin_amdgcn_mfma_f32_16x16x32_bf16(fA3, wf[0][3], bw0, 0,0,0);     \
      bw1 = __builtin_amdgcn_mfma_f32_16x16x32_bf16(fA3, wf[1][3], bw1, 0,0,0);     \
      bre0 = __builtin_amdgcn_mfma_f32_16x16x32_bf16(fX3, wrf[0][3], bre0, 0,0,0);  \
      bre1 = __builtin_amdgcn_mfma_f32_16x16x32_bf16(fX3, wrf[1][3], bre1, 0,0,0);  \
      float cf0 = (float)cnt[(GO) + rowbase + kq * 4 + 0];                          \
      float cf1 = (float)cnt[(GO) + rowbase + kq * 4 + 1];                          \
      float cf2 = (float)cnt[(GO) + rowbase + kq * 4 + 2];                          \
      float cf3 = (float)cnt[(GO) + rowbase + kq * 4 + 3];                          \
      u16* gp = gT + ((size_t)((GO) + rowbase + kq * 4) << 7) + t016 + r16;         \
      float g0, g1, g2, g3, ss, qq;                                                 \
      g0 = bw0[0] + cf0 * bvv0 + fmaxf(bre0[0] + brr0, 0.f);                        \
      g1 = bw0[1] + cf1 * bvv0 + fmaxf(bre0[1] + brr0, 0.f);                        \
      g2 = bw0[2] + cf2 * bvv0 + fmaxf(bre0[2] + brr0, 0.f);                        \
      g3 = bw0[3] + cf3 * bvv0 + fmaxf(bre0[3] + brr0, 0.f);                        \
      __builtin_nontemporal_store((u16)f2b(g0), gp + 0);                            \
      __builtin_nontemporal_store((u16)f2b(g1), gp + 128);                          \
      __builtin_nontemporal_store((u16)f2b(g2), gp + 256);                          \
      __builtin_nontemporal_store((u16)f2b(g3), gp + 384);                          \
      ss = g0 + g1 + g2 + g3;                                                       \
      qq = g0*g0 + g1*g1 + g2*g2 + g3*g3;                                           \
      if (TY) { sB0 += ss; qB0 += qq; } else { sA0 += ss; qA0 += qq; }              \
      g0 = bw1[0] + cf0 * bvv1 + fmaxf(bre1[0] + brr1, 0.f);                        \
      g1 = bw1[1] + cf1 * bvv1 + fmaxf(bre1[1] + brr1, 0.f);                        \
      g2 = bw1[2] + cf2 * bvv1 + fmaxf(bre1[2] + brr1, 0.f);                        \
      g3 = bw1[3] + cf3 * bvv1 + fmaxf(bre1[3] + brr1, 0.f);                        \
      __builtin_nontemporal_store((u16)f2b(g0), gp + 16);                           \
      __builtin_nontemporal_store((u16)f2b(g1), gp + 144);                          \
      __builtin_nontemporal_store((u16)f2b(g2), gp + 272);                          \
      __builtin_nontemporal_store((u16)f2b(g3), gp + 400);                          \
      ss = g0 + g1 + g2 + g3;                                                       \
      qq = g0*g0 + g1*g1 + g2*g2 + g3*g3;                                           \
      if (TY) { sB1 += ss; qB1 += qq; } else { sA1 += ss; qA1 += qq; }              \
    }                                                                               \
  }                                                                                 \
}

// ==== fused gather + GEMM: dbuf LDS, 1 barrier/chunk, 4-row MLP Phase A ====
__global__ __launch_bounds__(256) void k_fuse(
    const u16* __restrict__ xaT, const u16* __restrict__ xbT,
    const int* __restrict__ sorted, const int* __restrict__ off,
    const int* __restrict__ cnt, u16* __restrict__ gT,
    const u16* __restrict__ Wb, const u16* __restrict__ Wrb,
    const float* __restrict__ bb, const float* __restrict__ brb,
    float* __restrict__ stats) {
  __shared__ u16 aggL[2][64 * DF];   // 2 x 16 KB, swizzled at 16B-chunk granularity

  int tid = threadIdx.x;
  int lane = tid & 63;
  int wv = tid >> 6;            // wave 0..3 -> feature strip (Phase B)
  int r16 = lane & 15, kq = lane >> 4;
  int t016 = wv * 32;
  int qw = tid >> 4;            // quarter-wave 0..15
  int l16 = tid & 15;

  // weights resident in registers (64 VGPRs)
  bf16x8 wf[2][4], wrf[2][4];
#pragma unroll
  for (int ti = 0; ti < 2; ++ti) {
#pragma unroll
    for (int kk = 0; kk < 4; ++kk) {
      size_t o = (size_t)(t016 + ti * 16 + r16) * DF + kk * 32 + kq * 8;
      wf[ti][kk]  = *(const bf16x8*)(Wb + o);
      wrf[ti][kk] = *(const bf16x8*)(Wrb + o);
    }
  }
  float bvv0 = bb[t016 + r16],      brr0 = brb[t016 + r16];
  float bvv1 = bb[t016 + 16 + r16], brr1 = brb[t016 + 16 + r16];

  float sA0 = 0.f, sA1 = 0.f, qA0 = 0.f, qA1 = 0.f;
  float sB0 = 0.f, sB1 = 0.f, qB0 = 0.f, qB1 = 0.f;

  int pb = 0;
  int pTyp = 0, pNrows = 0, pGoff = 0, pBase = 0;
  const u16* pXsrc = xaT;
  bool hasPrev = false;

  for (int c = blockIdx.x; c < NCH; c += gridDim.x) {
    int typ, nrows, goff, base;
    if (c < NCHA) { typ = 0; nrows = NATOMS; goff = 0; base = c * 64; }
    else { typ = 1; nrows = NBONDS; goff = NATOMS; base = (c - NCHA) * 64; }
    const u16* gsrc = typ ? xaT : xbT;   // bond dst <- atom srcs; atom dst <- bond srcs
    const u16* xsrc = typ ? xbT : xaT;

    // ---- Phase A: gather 64 rows into aggL[pb]; quarter-wave owns 4 rows
    //      processed SIMULTANEOUSLY (4 independent load chains / iteration) ----
    {
      int vr0 = base + qw, vr1 = vr0 + 16, vr2 = vr0 + 32, vr3 = vr0 + 48;
      int s0 = 0, s1 = 0, s2 = 0, s3 = 0, d0 = 0, d1 = 0, d2 = 0, d3 = 0;
      if (vr0 < nrows) { s0 = off[goff + vr0]; d0 = cnt[goff + vr0]; }
      if (vr1 < nrows) { s1 = off[goff + vr1]; d1 = cnt[goff + vr1]; }
      if (vr2 < nrows) { s2 = off[goff + vr2]; d2 = cnt[goff + vr2]; }
      if (vr3 < nrows) { s3 = off[goff + vr3]; d3 = cnt[goff + vr3]; }
      float A0[8], A1[8], A2[8], A3[8];
#pragma unroll
      for (int j = 0; j < 8; ++j) { A0[j] = 0.f; A1[j] = 0.f; A2[j] = 0.f; A3[j] = 0.f; }
      int dmax = max(max(d0, d1), max(d2, d3));
      const u16* gp16 = gsrc + l16 * 8;
      for (int k = 0; k < dmax; ++k) {
        int i0 = (k < d0) ? sorted[s0 + k] : -1;
        int i1 = (k < d1) ? sorted[s1 + k] : -1;
        int i2 = (k < d2) ? sorted[s2 + k] : -1;
        int i3 = (k < d3) ? sorted[s3 + k] : -1;
        bf16x8 v0, v1, v2, v3;
        if (i0 >= 0) v0 = *(const bf16x8*)(gp16 + (size_t)i0 * DF);
        if (i1 >= 0) v1 = *(const bf16x8*)(gp16 + (size_t)i1 * DF);
        if (i2 >= 0) v2 = *(const bf16x8*)(gp16 + (size_t)i2 * DF);
        if (i3 >= 0) v3 = *(const bf16x8*)(gp16 + (size_t)i3 * DF);
        if (i0 >= 0) {
#pragma unroll
          for (int j = 0; j < 8; ++j) A0[j] += bf2f((u16)v0[j]);
        }
        if (i1 >= 0) {
#pragma unroll
          for (int j = 0; j < 8; ++j) A1[j] += bf2f((u16)v1[j]);
        }
        if (i2 >= 0) {
#pragma unroll
          for (int j = 0; j < 8; ++j) A2[j] += bf2f((u16)v2[j]);
        }
        if (i3 >= 0) {
#pragma unroll
          for (int j = 0; j < 8; ++j) A3[j] += bf2f((u16)v3[j]);
        }
      }
      int swz = (l16 ^ (qw & 7)) * 8;   // rows qw+16m share (row&7) == qw&7
      u16* bufp = aggL[pb];
      if (vr0 < nrows) {
        bf16x8 rr;
#pragma unroll
        for (int j = 0; j < 8; ++j) rr[j] = f2b(A0[j]);
        *(bf16x8*)(bufp + (qw +  0) * DF + swz) = rr;
      }
      if (vr1 < nrows) {
        bf16x8 rr;
#pragma unroll
        for (int j = 0; j < 8; ++j) rr[j] = f2b(A1[j]);
        *(bf16x8*)(bufp + (qw + 16) * DF + swz) = rr;
      }
      if (vr2 < nrows) {
        bf16x8 rr;
#pragma unroll
        for (int j = 0; j < 8; ++j) rr[j] = f2b(A2[j]);
        *(bf16x8*)(bufp + (qw + 32) * DF + swz) = rr;
      }
      if (vr3 < nrows) {
        bf16x8 rr;
#pragma unroll
        for (int j = 0; j < 8; ++j) rr[j] = f2b(A3[j]);
        *(bf16x8*)(bufp + (qw + 48) * DF + swz) = rr;
      }
    }

    // ---- Phase B for PREVIOUS chunk from the other buffer ----
    if (hasPrev) {
      PHASE_B(pTyp, pNrows, pGoff, pBase, pXsrc, aggL[pb ^ 1])
    }
    __syncthreads();   // aggL[pb] complete; aggL[pb^1] fully consumed

    pTyp = typ; pNrows = nrows; pGoff = goff; pBase = base; pXsrc = xsrc;
    hasPrev = true; pb ^= 1;
  }
  if (hasPrev) {
    PHASE_B(pTyp, pNrows, pGoff, pBase, pXsrc, aggL[pb ^ 1])
  }

  int bkt = blockIdx.x & (NBUCK - 1);
  float* p = stats + (size_t)bkt * 4 * DF;
  {
    float s0 = sA0, q0 = qA0, s1 = sB0, q1 = qB0;
    s0 += __shfl_xor(s0, 16); q0 += __shfl_xor(q0, 16);
    s1 += __shfl_xor(s1, 16); q1 += __shfl_xor(q1, 16);
    s0 += __shfl_xor(s0, 32); q0 += __shfl_xor(q0, 32);
    s1 += __shfl_xor(s1, 32); q1 += __shfl_xor(q1, 32);
    if (kq == 0) {
      int feat = t016 + r16;
      atomicAdd(p + 0 * DF + feat, s0);
      atomicAdd(p + 1 * DF + feat, q0);
      atomicAdd(p + 2 * DF + feat, s1);
      atomicAdd(p + 3 * DF + feat, q1);
    }
  }
  {
    float s0 = sA1, q0 = qA1, s1 = sB1, q1 = qB1;
    s0 += __shfl_xor(s0, 16); q0 += __shfl_xor(q0, 16);
    s1 += __shfl_xor(s1, 16); q1 += __shfl_xor(q1, 16);
    s0 += __shfl_xor(s0, 32); q0 += __shfl_xor(q0, 32);
    s1 += __shfl_xor(s1, 32); q1 += __shfl_xor(q1, 32);
    if (kq == 0) {
      int feat = t016 + 16 + r16;
      atomicAdd(p + 0 * DF + feat, s0);
      atomicAdd(p + 1 * DF + feat, q0);
      atomicAdd(p + 2 * DF + feat, s1);
      atomicAdd(p + 3 * DF + feat, q1);
    }
  }
}

// ---- fallback: gather fp32 ----
__global__ void k_gather_f(const float* __restrict__ xa, const float* __restrict__ xb,
                           const int* __restrict__ sorted, const int* __restrict__ off,
                           const int* __restrict__ cnt, float* __restrict__ outf) {
  int l32 = threadIdx.x & 31;
  int hwid = (blockIdx.x * blockDim.x + threadIdx.x) >> 5;
  int nhw = (gridDim.x * blockDim.x) >> 5;
  for (int g = hwid; g < NSEG; g += nhw) {
    int start = off[g], deg = cnt[g];
    const float* src = (g < NATOMS) ? xb : xa;
    float a0 = 0.f, a1 = 0.f, a2 = 0.f, a3 = 0.f;
    int k = 0;
    for (; k + 1 < deg; k += 2) {
      int s0 = sorted[start + k], s1 = sorted[start + k + 1];
      float4 v0 = *(const float4*)(src + (size_t)s0 * DF + l32 * 4);
      float4 v1 = *(const float4*)(src + (size_t)s1 * DF + l32 * 4);
      a0 += v0.x + v1.x; a1 += v0.y + v1.y; a2 += v0.z + v1.z; a3 += v0.w + v1.w;
    }
    if (k < deg) {
      int s0 = sorted[start + k];
      float4 v0 = *(const float4*)(src + (size_t)s0 * DF + l32 * 4);
      a0 += v0.x; a1 += v0.y; a2 += v0.z; a3 += v0.w;
    }
    float4 r; r.x = a0; r.y = a1; r.z = a2; r.w = a3;
    *(float4*)(outf + (size_t)g * DF + l32 * 4) = r;
  }
}

// ---- fallback GEMM (fp32 agg in outf, in place) ----
__global__ __launch_bounds__(256) void k_gemm0(
    const float* __restrict__ xa, const float* __restrict__ xb,
    float* __restrict__ outf, const int* __restrict__ cnt,
    const u16* __restrict__ Wb, const u16* __restrict__ Wrb,
    const float* __restrict__ bb, const float* __restrict__ brb,
    float* __restrict__ stats) {
  int lane = threadIdx.x & 63;
  int wv = threadIdx.x >> 6;
  int r16 = lane & 15, kq = lane >> 4;
  int t016 = wv * 32;

  bf16x8 wf[2][4], wrf[2][4];
#pragma unroll
  for (int ti = 0; ti < 2; ++ti) {
#pragma unroll
    for (int kk = 0; kk < 4; ++kk) {
      size_t o = (size_t)(t016 + ti * 16 + r16) * DF + kk * 32 + kq * 8;
      wf[ti][kk]  = *(const bf16x8*)(Wb + o);
      wrf[ti][kk] = *(const bf16x8*)(Wrb + o);
    }
  }
  float bvv[2] = { bb[t016 + r16], bb[t016 + 16 + r16] };
  float brr[2] = { brb[t016 + r16], brb[t016 + 16 + r16] };

  float sA[2] = {0.f, 0.f}, qA[2] = {0.f, 0.f};
  float sB[2] = {0.f, 0.f}, qB[2] = {0.f, 0.f};

  for (int c = blockIdx.x; c < NCH; c += gridDim.x) {
    int typ, nrows, goff, base;
    if (c < NCHA) { typ = 0; nrows = NATOMS; goff = 0; base = c * 64; }
    else { typ = 1; nrows = NBONDS; goff = NATOMS; base = (c - NCHA) * 64; }
    const float* xsrc = typ ? xb : xa;

#pragma unroll
    for (int rg = 0; rg < 4; ++rg) {
      int rowbase = base + rg * 16;
      if (rowbase < nrows) {
        int row = rowbase + r16;
        const float* ap = outf + (size_t)(goff + row) * DF + kq * 8;
        const float* xp = xsrc + (size_t)row * DF + kq * 8;
        bf16x8 fA[4], fX[4];
#pragma unroll
        for (int kk = 0; kk < 4; ++kk) {
          fA[kk] = pack8(*(const float4*)(ap + kk * 32), *(const float4*)(ap + kk * 32 + 4));
          fX[kk] = pack8(*(const float4*)(xp + kk * 32), *(const float4*)(xp + kk * 32 + 4));
        }
        __syncthreads();

        f32x4 accW[2], accR[2];
#pragma unroll
        for (int ti = 0; ti < 2; ++ti) {
#pragma unroll
          for (int r = 0; r < 4; ++r) { accW[ti][r] = 0.f; accR[ti][r] = 0.f; }
        }
#pragma unroll
        for (int kk = 0; kk < 4; ++kk) {
#pragma unroll
          for (int ti = 0; ti < 2; ++ti) {
            accW[ti] = __builtin_amdgcn_mfma_f32_16x16x32_bf16(fA[kk], wf[ti][kk], accW[ti], 0, 0, 0);
            accR[ti] = __builtin_amdgcn_mfma_f32_16x16x32_bf16(fX[kk], wrf[ti][kk], accR[ti], 0, 0, 0);
          }
        }
        float cf[4];
#pragma unroll
        for (int r = 0; r < 4; ++r)
          cf[r] = (float)cnt[goff + rowbase + kq * 4 + r];
#pragma unroll
        for (int ti = 0; ti < 2; ++ti) {
          int feat = t016 + ti * 16 + r16;
          float s = 0.f, q = 0.f;
#pragma unroll
          for (int r = 0; r < 4; ++r) {
            int grow = rowbase + kq * 4 + r;
            float gg = accW[ti][r] + cf[r] * bvv[ti] + fmaxf(accR[ti][r] + brr[ti], 0.f);
            outf[(size_t)(goff + grow) * DF + feat] = gg;
            s += gg; q += gg * gg;
          }
          if (typ == 0) { sA[ti] += s; qA[ti] += q; }
          else          { sB[ti] += s; qB[ti] += q; }
        }
      }
    }
  }

  int bkt = blockIdx.x & (NBUCK - 1);
  float* p = stats + (size_t)bkt * 4 * DF;
#pragma unroll
  for (int ti = 0; ti < 2; ++ti) {
    float s0 = sA[ti], q0 = qA[ti], s1 = sB[ti], q1 = qB[ti];
    s0 += __shfl_xor(s0, 16); q0 += __shfl_xor(q0, 16);
    s1 += __shfl_xor(s1, 16); q1 += __shfl_xor(q1, 16);
    s0 += __shfl_xor(s0, 32); q0 += __shfl_xor(q0, 32);
    s1 += __shfl_xor(s1, 32); q1 += __shfl_xor(q1, 32);
    if (kq == 0) {
      int feat = t016 + ti * 16 + r16;
      atomicAdd(p + 0 * DF + feat, s0);
      atomicAdd(p + 1 * DF + feat, q0);
      atomicAdd(p + 2 * DF + feat, s1);
      atomicAdd(p + 3 * DF + feat, q1);
    }
  }
}

// ---- finalize stats -> scale/shift ----
__global__ void k_stats(const float* __restrict__ stats,
                        const float* __restrict__ ga, const float* __restrict__ bea,
                        const float* __restrict__ gb, const float* __restrict__ beb,
                        float* __restrict__ scale, float* __restrict__ shift) {
  int tid = threadIdx.x;
  if (tid < 2 * DF) {
    int t = tid >> 7, f = tid & (DF - 1);
    float S = 0.f, SS = 0.f;
    for (int bk = 0; bk < NBUCK; ++bk) {
      const float* p = stats + (size_t)bk * 4 * DF;
      S  += p[(2 * t) * DF + f];
      SS += p[(2 * t + 1) * DF + f];
    }
    float n = t ? (float)NBONDS : (float)NATOMS;
    float mean = S / n;
    float var = SS / n - mean * mean;
    float rstd = rsqrtf(var + EPS);
    float g = t ? gb[f] : ga[f];
    float be = t ? beb[f] : bea[f];
    scale[tid] = rstd * g;
    shift[tid] = be - mean * rstd * g;
  }
}

// ---- normalize: TIER1 reads bf16 g (nt), writes fp32 out (nt); TIER0 in-place ----
template<int TIER>
__global__ void k_norm(float* __restrict__ out, const u16* __restrict__ gT,
                       const float* __restrict__ scale, const float* __restrict__ shift) {
  if constexpr (TIER) {
    const size_t nv = (size_t)NSEG * DF / 8;
    size_t stride = (size_t)gridDim.x * blockDim.x;
    for (size_t i = (size_t)blockIdx.x * blockDim.x + threadIdx.x; i < nv; i += stride) {
      size_t e = i * 8;
      int t = e >= (size_t)NATOMS * DF;
      int f = (int)(e & (DF - 1));
      bf16x8 v = __builtin_nontemporal_load((const bf16x8*)(gT + e));
      const float* sc = scale + t * DF + f;
      const float* sh = shift + t * DF + f;
      f32x4 o0, o1;
      o0[0] = fmaf(bf2f((u16)v[0]), sc[0], sh[0]);
      o0[1] = fmaf(bf2f((u16)v[1]), sc[1], sh[1]);
      o0[2] = fmaf(bf2f((u16)v[2]), sc[2], sh[2]);
      o0[3] = fmaf(bf2f((u16)v[3]), sc[3], sh[3]);
      o1[0] = fmaf(bf2f((u16)v[4]), sc[4], sh[4]);
      o1[1] = fmaf(bf2f((u16)v[5]), sc[5], sh[5]);
      o1[2] = fmaf(bf2f((u16)v[6]), sc[6], sh[6]);
      o1[3] = fmaf(bf2f((u16)v[7]), sc[7], sh[7]);
      __builtin_nontemporal_store(o0, (f32x4*)(out + e));
      __builtin_nontemporal_store(o1, (f32x4*)(out + e + 4));
    }
  } else {
    const size_t nv = (size_t)NSEG * DF / 4;
    size_t stride = (size_t)gridDim.x * blockDim.x;
    for (size_t i = (size_t)blockIdx.x * blockDim.x + threadIdx.x; i < nv; i += stride) {
      size_t e = i * 4;
      int t = e >= (size_t)NATOMS * DF;
      int f = (int)(e & (DF - 1));
      const float* sc = scale + t * DF + f;
      const float* sh = shift + t * DF + f;
      float4 v = ((float4*)out)[i];
      v.x = fmaf(v.x, sc[0], sh[0]);
      v.y = fmaf(v.y, sc[1], sh[1]);
      v.z = fmaf(v.z, sc[2], sh[2]);
      v.w = fmaf(v.w, sc[3], sh[3]);
      ((float4*)out)[i] = v;
    }
  }
}

extern "C" void kernel_launch(void* const* d_in, const int* in_sizes, int n_in,
                              void* d_out, int out_size, void* d_ws, size_t ws_size,
                              hipStream_t stream) {
  const float* xa  = (const float*)d_in[0];
  const float* xb  = (const float*)d_in[1];
  const int*   ab  = (const int*)d_in[2];
  const int*   ba  = (const int*)d_in[3];
  const float* W   = (const float*)d_in[4];
  const float* b   = (const float*)d_in[5];
  const float* Wr  = (const float*)d_in[6];
  const float* br  = (const float*)d_in[7];
  const float* ga  = (const float*)d_in[8];
  const float* bea = (const float*)d_in[9];
  const float* gb  = (const float*)d_in[10];
  const float* beb = (const float*)d_in[11];
  float* out = (float*)d_out;

  char* ws = (char*)d_ws;
  int*   cnt    = (int*)ws;                       // 2,000,000
  int*   off    = (int*)(ws +  2000000);          // 2,000,000
  int*   cursor = (int*)(ws +  4000000);          // 2,000,000
  int*   sorted = (int*)(ws +  6000000);          // 4,800,000
  float* stats  = (float*)(ws + 10800000);        // 65,536
  int*   bsum   = (int*)(ws + 10865536);          // 1,024
  int*   bbase  = (int*)(ws + 10866560);          // 1,024
  u16*   Wbf    = (u16*)(ws + 10867584);          // 32,768
  u16*   Wrbf   = (u16*)(ws + 10900352);          // 32,768
  float* scale  = (float*)(ws + 10933120);        // 1,024
  float* shift  = (float*)(ws + 10934144);        // 1,024
  u16*   gT   = (u16*)(ws + 10935168);            // 128,000,000
  u16*   xaT  = (u16*)(ws + 138935168);           //  51,200,000
  u16*   xbT  = (u16*)(ws + 190135168);           //  76,800,000 -> ends 266,935,168
  const bool xt = ws_size >= 266935168ull;        // bf16 tier

  hipMemsetAsync(cnt, 0, 2000000, stream);
  hipMemsetAsync(stats, 0, 65536, stream);

  if (xt) {
    k_setup<<<4672, 256, 0, stream>>>(xa, xb, xaT, xbT, ab, ba, cnt, W, Wr, Wbf, Wrbf);
  } else {
    k_prep<<<64, 256, 0, stream>>>(W, Wr, Wbf, Wrbf);
    k_hist<<<2048, 256, 0, stream>>>(ab, ba, cnt);
  }
  k_scanA<<<NSBLK, 256, 0, stream>>>(cnt, bsum);
  k_scanB<<<1, 256, 0, stream>>>(bsum, bbase);
  k_scanC<<<NSBLK, 256, 0, stream>>>(cnt, bbase, off, cursor);
  k_fill<<<2048, 256, 0, stream>>>(ab, ba, cursor, sorted);

  if (xt) {
    k_fuse<<<2048, 256, 0, stream>>>(xaT, xbT, sorted, off, cnt, gT,
                                     Wbf, Wrbf, b, br, stats);
    k_stats<<<1, 256, 0, stream>>>(stats, ga, bea, gb, beb, scale, shift);
    k_norm<1><<<4096, 256, 0, stream>>>(out, gT, scale, shift);
  } else {
    k_gather_f<<<8192, 256, 0, stream>>>(xa, xb, sorted, off, cnt, out);
    k_gemm0<<<2048, 256, 0, stream>>>(xa, xb, out, cnt, Wbf, Wrbf, b, br, stats);
    k_stats<<<1, 256, 0, stream>>>(stats, ga, bea, gb, beb, scale, shift);
    k_norm<0><<<8192, 256, 0, stream>>>(out, gT, scale, shift);
  }
}

// Round 14
// 514.950 us; speedup vs baseline: 1.1021x; 1.0051x over previous
//
#include <hip/hip_runtime.h>
#include <stdint.h>

#define NATOMS 200000
#define NBONDS 300000
#define NEDGE  600000
#define NSEG   (NATOMS + NBONDS)   // 500000
#define DF     128
#define EPS    1e-5f
#define SCHUNK 2048
#define NSBLK  ((NSEG + SCHUNK - 1) / SCHUNK)  // 245
#define NBUCK  32
#define NCHA   (NATOMS / 64)            // 3125 exact
#define NCHB   ((NBONDS + 63) / 64)     // 4688 (tail 32 rows = 2 full 16-row groups)
#define NCH    (NCHA + NCHB)            // 7813

typedef __attribute__((ext_vector_type(8))) short bf16x8;
typedef __attribute__((ext_vector_type(4))) float f32x4;
typedef unsigned short u16;

__device__ __forceinline__ short f2b(float f) {
  union { float f; uint32_t u; } v; v.f = f;
  uint32_t r = v.u + 0x7fffu + ((v.u >> 16) & 1u);
  return (short)(r >> 16);
}
__device__ __forceinline__ float bf2f(u16 h) {
  union { uint32_t u; float f; } v; v.u = ((uint32_t)h) << 16; return v.f;
}
__device__ __forceinline__ bf16x8 pack8(float4 u, float4 v) {
  bf16x8 t;
  t[0] = f2b(u.x); t[1] = f2b(u.y); t[2] = f2b(u.z); t[3] = f2b(u.w);
  t[4] = f2b(v.x); t[5] = f2b(v.y); t[6] = f2b(v.z); t[7] = f2b(v.w);
  return t;
}

// ---- weights -> bf16 (fallback tier only; xt tier folds this into k_setup) ----
__global__ void k_prep(const float* __restrict__ W, const float* __restrict__ Wr,
                       u16* __restrict__ Wb, u16* __restrict__ Wrb) {
  int i = blockIdx.x * blockDim.x + threadIdx.x;
  if (i < DF * DF) {
    Wb[i]  = (u16)f2b(W[i]);
    Wrb[i] = (u16)f2b(Wr[i]);
  }
}

// ---- fused setup: conv x->xT (0..4095) + hist (4096..4607) + weights (4608..4671) ----
__global__ void k_setup(const float* __restrict__ xa, const float* __restrict__ xb,
                        u16* __restrict__ xaT, u16* __restrict__ xbT,
                        const int* __restrict__ ab, const int* __restrict__ ba,
                        int* __restrict__ cnt,
                        const float* __restrict__ W, const float* __restrict__ Wr,
                        u16* __restrict__ Wb, u16* __restrict__ Wrb) {
  const int NA8 = NATOMS * DF / 8;   // 3,200,000
  const int NT8 = NSEG * DF / 8;     // 8,000,000
  int bid = blockIdx.x;
  if (bid < 4096) {
    int stride = 4096 * 256;
    for (int i = bid * 256 + threadIdx.x; i < NT8; i += stride) {
      const float* src; u16* dst; int j;
      if (i < NA8) { src = xa; dst = xaT; j = i; }
      else { src = xb; dst = xbT; j = i - NA8; }
      const float4 a = *(const float4*)(src + (size_t)j * 8);
      const float4 b = *(const float4*)(src + (size_t)j * 8 + 4);
      *(bf16x8*)(dst + (size_t)j * 8) = pack8(a, b);
    }
  } else if (bid < 4608) {
    int stride = 512 * 256;
    for (int e = (bid - 4096) * 256 + threadIdx.x; e < 2 * NEDGE; e += stride) {
      int g;
      if (e < NEDGE) g = NATOMS + ab[NEDGE + e];
      else           g = ba[NEDGE + (e - NEDGE)];
      atomicAdd(cnt + g, 1);
    }
  } else {
    int i = (bid - 4608) * 256 + threadIdx.x;
    if (i < DF * DF) {
      Wb[i]  = (u16)f2b(W[i]);
      Wrb[i] = (u16)f2b(Wr[i]);
    }
  }
}

// ---- plain hist (fallback tier) ----
__global__ void k_hist(const int* __restrict__ ab, const int* __restrict__ ba,
                       int* __restrict__ cnt) {
  int stride = gridDim.x * blockDim.x;
  for (int e = blockIdx.x * blockDim.x + threadIdx.x; e < 2 * NEDGE; e += stride) {
    int g;
    if (e < NEDGE) g = NATOMS + ab[NEDGE + e];
    else           g = ba[NEDGE + (e - NEDGE)];
    atomicAdd(cnt + g, 1);
  }
}

// ---- 3-phase exclusive scan ----
__global__ void k_scanA(const int* __restrict__ cnt, int* __restrict__ bsum) {
  __shared__ int wsm[4];
  int t = threadIdx.x;
  int base = blockIdx.x * SCHUNK + t * 8;
  int s = 0;
#pragma unroll
  for (int j = 0; j < 8; ++j) { int i = base + j; if (i < NSEG) s += cnt[i]; }
  for (int d = 1; d < 64; d <<= 1) s += __shfl_xor(s, d);
  if ((t & 63) == 0) wsm[t >> 6] = s;
  __syncthreads();
  if (t == 0) bsum[blockIdx.x] = wsm[0] + wsm[1] + wsm[2] + wsm[3];
}

__global__ void k_scanB(const int* __restrict__ bsum, int* __restrict__ bbase) {
  __shared__ int wsm[4];
  int t = threadIdx.x;
  int lane = t & 63;
  int v = (t < NSBLK) ? bsum[t] : 0;
  int s = v;
  for (int d = 1; d < 64; d <<= 1) { int n = __shfl_up(s, d); if (lane >= d) s += n; }
  if (lane == 63) wsm[t >> 6] = s;
  __syncthreads();
  int wbase = 0;
  for (int w = 0; w < (t >> 6); ++w) wbase += wsm[w];
  if (t < NSBLK) bbase[t] = wbase + s - v;
}

__global__ void k_scanC(const int* __restrict__ cnt, const int* __restrict__ bbase,
                        int* __restrict__ off, int* __restrict__ cursor) {
  __shared__ int wsm[4];
  int t = threadIdx.x;
  int lane = t & 63, wv = t >> 6;
  int base = blockIdx.x * SCHUNK + t * 8;
  int v[8]; int ts = 0;
#pragma unroll
  for (int j = 0; j < 8; ++j) { int i = base + j; v[j] = (i < NSEG) ? cnt[i] : 0; ts += v[j]; }
  int s = ts;
  for (int d = 1; d < 64; d <<= 1) { int n = __shfl_up(s, d); if (lane >= d) s += n; }
  if (lane == 63) wsm[wv] = s;
  __syncthreads();
  int wbase = bbase[blockIdx.x];
  for (int w = 0; w < wv; ++w) wbase += wsm[w];
  int run = wbase + s - ts;
#pragma unroll
  for (int j = 0; j < 8; ++j) {
    int i = base + j;
    if (i < NSEG) { off[i] = run; cursor[i] = run; }
    run += v[j];
  }
}

// ---- bucket src indices per dst ----
__global__ void k_fill(const int* __restrict__ ab, const int* __restrict__ ba,
                       int* __restrict__ cursor, int* __restrict__ sorted) {
  int stride = gridDim.x * blockDim.x;
  for (int e = blockIdx.x * blockDim.x + threadIdx.x; e < 2 * NEDGE; e += stride) {
    int g, src;
    if (e < NEDGE) { g = NATOMS + ab[NEDGE + e]; src = ab[e]; }
    else { int e2 = e - NEDGE; g = ba[NEDGE + e2]; src = ba[e2]; }
    int pos = atomicAdd(cursor + g, 1);
    sorted[pos] = src;
  }
}

// Phase B body: MFMA for chunk (TY,NR,GO,BA) reading agg tile BUF, x from XS.
// gT stores are regular (cached) — they coalesce in L2; nt amplified WRITE by 30% (r13).
#define PHASE_B(TY, NR, GO, BA, XS, BUF) {                                          \
  _Pragma("unroll")                                                                 \
  for (int rg = 0; rg < 4; ++rg) {                                                  \
    int rowbase = (BA) + rg * 16;                                                   \
    if (rowbase < (NR)) {                                                           \
      int lrow = rg * 16 + r16;                                                     \
      int sx = r16 & 7;                                                             \
      bf16x8 fA0 = *(const bf16x8*)((BUF) + lrow * DF + (((0  + kq) ^ sx) * 8));    \
      bf16x8 fA1 = *(const bf16x8*)((BUF) + lrow * DF + (((4  + kq) ^ sx) * 8));    \
      bf16x8 fA2 = *(const bf16x8*)((BUF) + lrow * DF + (((8  + kq) ^ sx) * 8));    \
      bf16x8 fA3 = *(const bf16x8*)((BUF) + lrow * DF + (((12 + kq) ^ sx) * 8));    \
      const u16* xp_ = (XS) + (size_t)(rowbase + r16) * DF + kq * 8;                \
      bf16x8 fX0 = *(const bf16x8*)(xp_);                                           \
      bf16x8 fX1 = *(const bf16x8*)(xp_ + 32);                                      \
      bf16x8 fX2 = *(const bf16x8*)(xp_ + 64);                                      \
      bf16x8 fX3 = *(const bf16x8*)(xp_ + 96);                                      \
      f32x4 bw0 = {0.f,0.f,0.f,0.f}, bw1 = {0.f,0.f,0.f,0.f};                       \
      f32x4 bre0 = {0.f,0.f,0.f,0.f}, bre1 = {0.f,0.f,0.f,0.f};                     \
      bw0 = __builtin_amdgcn_mfma_f32_16x16x32_bf16(fA0, wf[0][0], bw0, 0,0,0);     \
      bw1 = __builtin_amdgcn_mfma_f32_16x16x32_bf16(fA0, wf[1][0], bw1, 0,0,0);     \
      bre0 = __builtin_amdgcn_mfma_f32_16x16x32_bf16(fX0, wrf[0][0], bre0, 0,0,0);  \
      bre1 = __builtin_amdgcn_mfma_f32_16x16x32_bf16(fX0, wrf[1][0], bre1, 0,0,0);  \
      bw0 = __builtin_amdgcn_mfma_f32_16x16x32_bf16(fA1, wf[0][1], bw0, 0,0,0);     \
      bw1 = __builtin_amdgcn_mfma_f32_16x16x32_bf16(fA1, wf[1][1], bw1, 0,0,0);     \
      bre0 = __builtin_amdgcn_mfma_f32_16x16x32_bf16(fX1, wrf[0][1], bre0, 0,0,0);  \
      bre1 = __builtin_amdgcn_mfma_f32_16x16x32_bf16(fX1, wrf[1][1], bre1, 0,0,0);  \
      bw0 = __builtin_amdgcn_mfma_f32_16x16x32_bf16(fA2, wf[0][2], bw0, 0,0,0);     \
      bw1 = __builtin_amdgcn_mfma_f32_16x16x32_bf16(fA2, wf[1][2], bw1, 0,0,0);     \
      bre0 = __builtin_amdgcn_mfma_f32_16x16x32_bf16(fX2, wrf[0][2], bre0, 0,0,0);  \
      bre1 = __builtin_amdgcn_mfma_f32_16x16x32_bf16(fX2, wrf[1][2], bre1, 0,0,0);  \
      bw0 = __builtin_amdgcn_mfma_f32_16x16x32_bf16(fA3, wf[0][3], bw0, 0,0,0);     \
      bw1 = __builtin_amdgcn_mfma_f32_16x16x32_bf16(fA3, wf[1][3], bw1, 0,0,0);     \
      bre0 = __builtin_amdgcn_mfma_f32_16x16x32_bf16(fX3, wrf[0][3], bre0, 0,0,0);  \
      bre1 = __builtin_amdgcn_mfma_f32_16x16x32_bf16(fX3, wrf[1][3], bre1, 0,0,0);  \
      float cf0 = (float)cnt[(GO) + rowbase + kq * 4 + 0];                          \
      float cf1 = (float)cnt[(GO) + rowbase + kq * 4 + 1];                          \
      float cf2 = (float)cnt[(GO) + rowbase + kq * 4 + 2];                          \
      float cf3 = (float)cnt[(GO) + rowbase + kq * 4 + 3];                          \
      u16* gp = gT + ((size_t)((GO) + rowbase + kq * 4) << 7) + t016 + r16;         \
      float g0, g1, g2, g3, ss, qq;                                                 \
      g0 = bw0[0] + cf0 * bvv0 + fmaxf(bre0[0] + brr0, 0.f);                        \
      g1 = bw0[1] + cf1 * bvv0 + fmaxf(bre0[1] + brr0, 0.f);                        \
      g2 = bw0[2] + cf2 * bvv0 + fmaxf(bre0[2] + brr0, 0.f);                        \
      g3 = bw0[3] + cf3 * bvv0 + fmaxf(bre0[3] + brr0, 0.f);                        \
      gp[0]   = (u16)f2b(g0); gp[128] = (u16)f2b(g1);                               \
      gp[256] = (u16)f2b(g2); gp[384] = (u16)f2b(g3);                               \
      ss = g0 + g1 + g2 + g3;                                                       \
      qq = g0*g0 + g1*g1 + g2*g2 + g3*g3;                                           \
      if (TY) { sB0 += ss; qB0 += qq; } else { sA0 += ss; qA0 += qq; }              \
      g0 = bw1[0] + cf0 * bvv1 + fmaxf(bre1[0] + brr1, 0.f);                        \
      g1 = bw1[1] + cf1 * bvv1 + fmaxf(bre1[1] + brr1, 0.f);                        \
      g2 = bw1[2] + cf2 * bvv1 + fmaxf(bre1[2] + brr1, 0.f);                        \
      g3 = bw1[3] + cf3 * bvv1 + fmaxf(bre1[3] + brr1, 0.f);                        \
      gp[16]  = (u16)f2b(g0); gp[144] = (u16)f2b(g1);                               \
      gp[272] = (u16)f2b(g2); gp[400] = (u16)f2b(g3);                               \
      ss = g0 + g1 + g2 + g3;                                                       \
      qq = g0*g0 + g1*g1 + g2*g2 + g3*g3;                                           \
      if (TY) { sB1 += ss; qB1 += qq; } else { sA1 += ss; qA1 += qq; }              \
    }                                                                               \
  }                                                                                 \
}

// ==== fused gather + GEMM: dbuf LDS, 1 barrier/chunk, 4-row MLP Phase A ====
__global__ __launch_bounds__(256) void k_fuse(
    const u16* __restrict__ xaT, const u16* __restrict__ xbT,
    const int* __restrict__ sorted, const int* __restrict__ off,
    const int* __restrict__ cnt, u16* __restrict__ gT,
    const u16* __restrict__ Wb, const u16* __restrict__ Wrb,
    const float* __restrict__ bb, const float* __restrict__ brb,
    float* __restrict__ stats) {
  __shared__ u16 aggL[2][64 * DF];   // 2 x 16 KB, swizzled at 16B-chunk granularity

  int tid = threadIdx.x;
  int lane = tid & 63;
  int wv = tid >> 6;            // wave 0..3 -> feature strip (Phase B)
  int r16 = lane & 15, kq = lane >> 4;
  int t016 = wv * 32;
  int qw = tid >> 4;            // quarter-wave 0..15
  int l16 = tid & 15;

  // weights resident in registers (64 VGPRs)
  bf16x8 wf[2][4], wrf[2][4];
#pragma unroll
  for (int ti = 0; ti < 2; ++ti) {
#pragma unroll
    for (int kk = 0; kk < 4; ++kk) {
      size_t o = (size_t)(t016 + ti * 16 + r16) * DF + kk * 32 + kq * 8;
      wf[ti][kk]  = *(const bf16x8*)(Wb + o);
      wrf[ti][kk] = *(const bf16x8*)(Wrb + o);
    }
  }
  float bvv0 = bb[t016 + r16],      brr0 = brb[t016 + r16];
  float bvv1 = bb[t016 + 16 + r16], brr1 = brb[t016 + 16 + r16];

  float sA0 = 0.f, sA1 = 0.f, qA0 = 0.f, qA1 = 0.f;
  float sB0 = 0.f, sB1 = 0.f, qB0 = 0.f, qB1 = 0.f;

  int pb = 0;
  int pTyp = 0, pNrows = 0, pGoff = 0, pBase = 0;
  const u16* pXsrc = xaT;
  bool hasPrev = false;

  for (int c = blockIdx.x; c < NCH; c += gridDim.x) {
    int typ, nrows, goff, base;
    if (c < NCHA) { typ = 0; nrows = NATOMS; goff = 0; base = c * 64; }
    else { typ = 1; nrows = NBONDS; goff = NATOMS; base = (c - NCHA) * 64; }
    const u16* gsrc = typ ? xaT : xbT;   // bond dst <- atom srcs; atom dst <- bond srcs
    const u16* xsrc = typ ? xbT : xaT;

    // ---- Phase A: gather 64 rows into aggL[pb]; quarter-wave owns 4 rows
    //      processed SIMULTANEOUSLY (4 independent load chains / iteration) ----
    {
      int vr0 = base + qw, vr1 = vr0 + 16, vr2 = vr0 + 32, vr3 = vr0 + 48;
      int s0 = 0, s1 = 0, s2 = 0, s3 = 0, d0 = 0, d1 = 0, d2 = 0, d3 = 0;
      if (vr0 < nrows) { s0 = off[goff + vr0]; d0 = cnt[goff + vr0]; }
      if (vr1 < nrows) { s1 = off[goff + vr1]; d1 = cnt[goff + vr1]; }
      if (vr2 < nrows) { s2 = off[goff + vr2]; d2 = cnt[goff + vr2]; }
      if (vr3 < nrows) { s3 = off[goff + vr3]; d3 = cnt[goff + vr3]; }
      float A0[8], A1[8], A2[8], A3[8];
#pragma unroll
      for (int j = 0; j < 8; ++j) { A0[j] = 0.f; A1[j] = 0.f; A2[j] = 0.f; A3[j] = 0.f; }
      int dmax = max(max(d0, d1), max(d2, d3));
      const u16* gp16 = gsrc + l16 * 8;
      for (int k = 0; k < dmax; ++k) {
        int i0 = (k < d0) ? sorted[s0 + k] : -1;
        int i1 = (k < d1) ? sorted[s1 + k] : -1;
        int i2 = (k < d2) ? sorted[s2 + k] : -1;
        int i3 = (k < d3) ? sorted[s3 + k] : -1;
        bf16x8 v0, v1, v2, v3;
        if (i0 >= 0) v0 = *(const bf16x8*)(gp16 + (size_t)i0 * DF);
        if (i1 >= 0) v1 = *(const bf16x8*)(gp16 + (size_t)i1 * DF);
        if (i2 >= 0) v2 = *(const bf16x8*)(gp16 + (size_t)i2 * DF);
        if (i3 >= 0) v3 = *(const bf16x8*)(gp16 + (size_t)i3 * DF);
        if (i0 >= 0) {
#pragma unroll
          for (int j = 0; j < 8; ++j) A0[j] += bf2f((u16)v0[j]);
        }
        if (i1 >= 0) {
#pragma unroll
          for (int j = 0; j < 8; ++j) A1[j] += bf2f((u16)v1[j]);
        }
        if (i2 >= 0) {
#pragma unroll
          for (int j = 0; j < 8; ++j) A2[j] += bf2f((u16)v2[j]);
        }
        if (i3 >= 0) {
#pragma unroll
          for (int j = 0; j < 8; ++j) A3[j] += bf2f((u16)v3[j]);
        }
      }
      int swz = (l16 ^ (qw & 7)) * 8;   // rows qw+16m share (row&7) == qw&7
      u16* bufp = aggL[pb];
      if (vr0 < nrows) {
        bf16x8 rr;
#pragma unroll
        for (int j = 0; j < 8; ++j) rr[j] = f2b(A0[j]);
        *(bf16x8*)(bufp + (qw +  0) * DF + swz) = rr;
      }
      if (vr1 < nrows) {
        bf16x8 rr;
#pragma unroll
        for (int j = 0; j < 8; ++j) rr[j] = f2b(A1[j]);
        *(bf16x8*)(bufp + (qw + 16) * DF + swz) = rr;
      }
      if (vr2 < nrows) {
        bf16x8 rr;
#pragma unroll
        for (int j = 0; j < 8; ++j) rr[j] = f2b(A2[j]);
        *(bf16x8*)(bufp + (qw + 32) * DF + swz) = rr;
      }
      if (vr3 < nrows) {
        bf16x8 rr;
#pragma unroll
        for (int j = 0; j < 8; ++j) rr[j] = f2b(A3[j]);
        *(bf16x8*)(bufp + (qw + 48) * DF + swz) = rr;
      }
    }

    // ---- Phase B for PREVIOUS chunk from the other buffer ----
    if (hasPrev) {
      PHASE_B(pTyp, pNrows, pGoff, pBase, pXsrc, aggL[pb ^ 1])
    }
    __syncthreads();   // aggL[pb] complete; aggL[pb^1] fully consumed

    pTyp = typ; pNrows = nrows; pGoff = goff; pBase = base; pXsrc = xsrc;
    hasPrev = true; pb ^= 1;
  }
  if (hasPrev) {
    PHASE_B(pTyp, pNrows, pGoff, pBase, pXsrc, aggL[pb ^ 1])
  }

  int bkt = blockIdx.x & (NBUCK - 1);
  float* p = stats + (size_t)bkt * 4 * DF;
  {
    float s0 = sA0, q0 = qA0, s1 = sB0, q1 = qB0;
    s0 += __shfl_xor(s0, 16); q0 += __shfl_xor(q0, 16);
    s1 += __shfl_xor(s1, 16); q1 += __shfl_xor(q1, 16);
    s0 += __shfl_xor(s0, 32); q0 += __shfl_xor(q0, 32);
    s1 += __shfl_xor(s1, 32); q1 += __shfl_xor(q1, 32);
    if (kq == 0) {
      int feat = t016 + r16;
      atomicAdd(p + 0 * DF + feat, s0);
      atomicAdd(p + 1 * DF + feat, q0);
      atomicAdd(p + 2 * DF + feat, s1);
      atomicAdd(p + 3 * DF + feat, q1);
    }
  }
  {
    float s0 = sA1, q0 = qA1, s1 = sB1, q1 = qB1;
    s0 += __shfl_xor(s0, 16); q0 += __shfl_xor(q0, 16);
    s1 += __shfl_xor(s1, 16); q1 += __shfl_xor(q1, 16);
    s0 += __shfl_xor(s0, 32); q0 += __shfl_xor(q0, 32);
    s1 += __shfl_xor(s1, 32); q1 += __shfl_xor(q1, 32);
    if (kq == 0) {
      int feat = t016 + 16 + r16;
      atomicAdd(p + 0 * DF + feat, s0);
      atomicAdd(p + 1 * DF + feat, q0);
      atomicAdd(p + 2 * DF + feat, s1);
      atomicAdd(p + 3 * DF + feat, q1);
    }
  }
}

// ---- fallback: gather fp32 ----
__global__ void k_gather_f(const float* __restrict__ xa, const float* __restrict__ xb,
                           const int* __restrict__ sorted, const int* __restrict__ off,
                           const int* __restrict__ cnt, float* __restrict__ outf) {
  int l32 = threadIdx.x & 31;
  int hwid = (blockIdx.x * blockDim.x + threadIdx.x) >> 5;
  int nhw = (gridDim.x * blockDim.x) >> 5;
  for (int g = hwid; g < NSEG; g += nhw) {
    int start = off[g], deg = cnt[g];
    const float* src = (g < NATOMS) ? xb : xa;
    float a0 = 0.f, a1 = 0.f, a2 = 0.f, a3 = 0.f;
    int k = 0;
    for (; k + 1 < deg; k += 2) {
      int s0 = sorted[start + k], s1 = sorted[start + k + 1];
      float4 v0 = *(const float4*)(src + (size_t)s0 * DF + l32 * 4);
      float4 v1 = *(const float4*)(src + (size_t)s1 * DF + l32 * 4);
      a0 += v0.x + v1.x; a1 += v0.y + v1.y; a2 += v0.z + v1.z; a3 += v0.w + v1.w;
    }
    if (k < deg) {
      int s0 = sorted[start + k];
      float4 v0 = *(const float4*)(src + (size_t)s0 * DF + l32 * 4);
      a0 += v0.x; a1 += v0.y; a2 += v0.z; a3 += v0.w;
    }
    float4 r; r.x = a0; r.y = a1; r.z = a2; r.w = a3;
    *(float4*)(outf + (size_t)g * DF + l32 * 4) = r;
  }
}

// ---- fallback GEMM (fp32 agg in outf, in place) ----
__global__ __launch_bounds__(256) void k_gemm0(
    const float* __restrict__ xa, const float* __restrict__ xb,
    float* __restrict__ outf, const int* __restrict__ cnt,
    const u16* __restrict__ Wb, const u16* __restrict__ Wrb,
    const float* __restrict__ bb, const float* __restrict__ brb,
    float* __restrict__ stats) {
  int lane = threadIdx.x & 63;
  int wv = threadIdx.x >> 6;
  int r16 = lane & 15, kq = lane >> 4;
  int t016 = wv * 32;

  bf16x8 wf[2][4], wrf[2][4];
#pragma unroll
  for (int ti = 0; ti < 2; ++ti) {
#pragma unroll
    for (int kk = 0; kk < 4; ++kk) {
      size_t o = (size_t)(t016 + ti * 16 + r16) * DF + kk * 32 + kq * 8;
      wf[ti][kk]  = *(const bf16x8*)(Wb + o);
      wrf[ti][kk] = *(const bf16x8*)(Wrb + o);
    }
  }
  float bvv[2] = { bb[t016 + r16], bb[t016 + 16 + r16] };
  float brr[2] = { brb[t016 + r16], brb[t016 + 16 + r16] };

  float sA[2] = {0.f, 0.f}, qA[2] = {0.f, 0.f};
  float sB[2] = {0.f, 0.f}, qB[2] = {0.f, 0.f};

  for (int c = blockIdx.x; c < NCH; c += gridDim.x) {
    int typ, nrows, goff, base;
    if (c < NCHA) { typ = 0; nrows = NATOMS; goff = 0; base = c * 64; }
    else { typ = 1; nrows = NBONDS; goff = NATOMS; base = (c - NCHA) * 64; }
    const float* xsrc = typ ? xb : xa;

#pragma unroll
    for (int rg = 0; rg < 4; ++rg) {
      int rowbase = base + rg * 16;
      if (rowbase < nrows) {
        int row = rowbase + r16;
        const float* ap = outf + (size_t)(goff + row) * DF + kq * 8;
        const float* xp = xsrc + (size_t)row * DF + kq * 8;
        bf16x8 fA[4], fX[4];
#pragma unroll
        for (int kk = 0; kk < 4; ++kk) {
          fA[kk] = pack8(*(const float4*)(ap + kk * 32), *(const float4*)(ap + kk * 32 + 4));
          fX[kk] = pack8(*(const float4*)(xp + kk * 32), *(const float4*)(xp + kk * 32 + 4));
        }
        __syncthreads();

        f32x4 accW[2], accR[2];
#pragma unroll
        for (int ti = 0; ti < 2; ++ti) {
#pragma unroll
          for (int r = 0; r < 4; ++r) { accW[ti][r] = 0.f; accR[ti][r] = 0.f; }
        }
#pragma unroll
        for (int kk = 0; kk < 4; ++kk) {
#pragma unroll
          for (int ti = 0; ti < 2; ++ti) {
            accW[ti] = __builtin_amdgcn_mfma_f32_16x16x32_bf16(fA[kk], wf[ti][kk], accW[ti], 0, 0, 0);
            accR[ti] = __builtin_amdgcn_mfma_f32_16x16x32_bf16(fX[kk], wrf[ti][kk], accR[ti], 0, 0, 0);
          }
        }
        float cf[4];
#pragma unroll
        for (int r = 0; r < 4; ++r)
          cf[r] = (float)cnt[goff + rowbase + kq * 4 + r];
#pragma unroll
        for (int ti = 0; ti < 2; ++ti) {
          int feat = t016 + ti * 16 + r16;
          float s = 0.f, q = 0.f;
#pragma unroll
          for (int r = 0; r < 4; ++r) {
            int grow = rowbase + kq * 4 + r;
            float gg = accW[ti][r] + cf[r] * bvv[ti] + fmaxf(accR[ti][r] + brr[ti], 0.f);
            outf[(size_t)(goff + grow) * DF + feat] = gg;
            s += gg; q += gg * gg;
          }
          if (typ == 0) { sA[ti] += s; qA[ti] += q; }
          else          { sB[ti] += s; qB[ti] += q; }
        }
      }
    }
  }

  int bkt = blockIdx.x & (NBUCK - 1);
  float* p = stats + (size_t)bkt * 4 * DF;
#pragma unroll
  for (int ti = 0; ti < 2; ++ti) {
    float s0 = sA[ti], q0 = qA[ti], s1 = sB[ti], q1 = qB[ti];
    s0 += __shfl_xor(s0, 16); q0 += __shfl_xor(q0, 16);
    s1 += __shfl_xor(s1, 16); q1 += __shfl_xor(q1, 16);
    s0 += __shfl_xor(s0, 32); q0 += __shfl_xor(q0, 32);
    s1 += __shfl_xor(s1, 32); q1 += __shfl_xor(q1, 32);
    if (kq == 0) {
      int feat = t016 + ti * 16 + r16;
      atomicAdd(p + 0 * DF + feat, s0);
      atomicAdd(p + 1 * DF + feat, q0);
      atomicAdd(p + 2 * DF + feat, s1);
      atomicAdd(p + 3 * DF + feat, q1);
    }
  }
}

// ---- finalize stats -> scale/shift ----
__global__ void k_stats(const float* __restrict__ stats,
                        const float* __restrict__ ga, const float* __restrict__ bea,
                        const float* __restrict__ gb, const float* __restrict__ beb,
                        float* __restrict__ scale, float* __restrict__ shift) {
  int tid = threadIdx.x;
  if (tid < 2 * DF) {
    int t = tid >> 7, f = tid & (DF - 1);
    float S = 0.f, SS = 0.f;
    for (int bk = 0; bk < NBUCK; ++bk) {
      const float* p = stats + (size_t)bk * 4 * DF;
      S  += p[(2 * t) * DF + f];
      SS += p[(2 * t + 1) * DF + f];
    }
    float n = t ? (float)NBONDS : (float)NATOMS;
    float mean = S / n;
    float var = SS / n - mean * mean;
    float rstd = rsqrtf(var + EPS);
    float g = t ? gb[f] : ga[f];
    float be = t ? beb[f] : bea[f];
    scale[tid] = rstd * g;
    shift[tid] = be - mean * rstd * g;
  }
}

// ---- normalize: TIER1 reads bf16 g (nt), writes fp32 out (nt); TIER0 in-place ----
template<int TIER>
__global__ void k_norm(float* __restrict__ out, const u16* __restrict__ gT,
                       const float* __restrict__ scale, const float* __restrict__ shift) {
  if constexpr (TIER) {
    const size_t nv = (size_t)NSEG * DF / 8;
    size_t stride = (size_t)gridDim.x * blockDim.x;
    for (size_t i = (size_t)blockIdx.x * blockDim.x + threadIdx.x; i < nv; i += stride) {
      size_t e = i * 8;
      int t = e >= (size_t)NATOMS * DF;
      int f = (int)(e & (DF - 1));
      bf16x8 v = __builtin_nontemporal_load((const bf16x8*)(gT + e));
      const float* sc = scale + t * DF + f;
      const float* sh = shift + t * DF + f;
      f32x4 o0, o1;
      o0[0] = fmaf(bf2f((u16)v[0]), sc[0], sh[0]);
      o0[1] = fmaf(bf2f((u16)v[1]), sc[1], sh[1]);
      o0[2] = fmaf(bf2f((u16)v[2]), sc[2], sh[2]);
      o0[3] = fmaf(bf2f((u16)v[3]), sc[3], sh[3]);
      o1[0] = fmaf(bf2f((u16)v[4]), sc[4], sh[4]);
      o1[1] = fmaf(bf2f((u16)v[5]), sc[5], sh[5]);
      o1[2] = fmaf(bf2f((u16)v[6]), sc[6], sh[6]);
      o1[3] = fmaf(bf2f((u16)v[7]), sc[7], sh[7]);
      __builtin_nontemporal_store(o0, (f32x4*)(out + e));
      __builtin_nontemporal_store(o1, (f32x4*)(out + e + 4));
    }
  } else {
    const size_t nv = (size_t)NSEG * DF / 4;
    size_t stride = (size_t)gridDim.x * blockDim.x;
    for (size_t i = (size_t)blockIdx.x * blockDim.x + threadIdx.x; i < nv; i += stride) {
      size_t e = i * 4;
      int t = e >= (size_t)NATOMS * DF;
      int f = (int)(e & (DF - 1));
      const float* sc = scale + t * DF + f;
      const float* sh = shift + t * DF + f;
      float4 v = ((float4*)out)[i];
      v.x = fmaf(v.x, sc[0], sh[0]);
      v.y = fmaf(v.y, sc[1], sh[1]);
      v.z = fmaf(v.z, sc[2], sh[2]);
      v.w = fmaf(v.w, sc[3], sh[3]);
      ((float4*)out)[i] = v;
    }
  }
}

extern "C" void kernel_launch(void* const* d_in, const int* in_sizes, int n_in,
                              void* d_out, int out_size, void* d_ws, size_t ws_size,
                              hipStream_t stream) {
  const float* xa  = (const float*)d_in[0];
  const float* xb  = (const float*)d_in[1];
  const int*   ab  = (const int*)d_in[2];
  const int*   ba  = (const int*)d_in[3];
  const float* W   = (const float*)d_in[4];
  const float* b   = (const float*)d_in[5];
  const float* Wr  = (const float*)d_in[6];
  const float* br  = (const float*)d_in[7];
  const float* ga  = (const float*)d_in[8];
  const float* bea = (const float*)d_in[9];
  const float* gb  = (const float*)d_in[10];
  const float* beb = (const float*)d_in[11];
  float* out = (float*)d_out;

  char* ws = (char*)d_ws;
  int*   cnt    = (int*)ws;                       // 2,000,000
  int*   off    = (int*)(ws +  2000000);          // 2,000,000
  int*   cursor = (int*)(ws +  4000000);          // 2,000,000
  int*   sorted = (int*)(ws +  6000000);          // 4,800,000
  float* stats  = (float*)(ws + 10800000);        // 65,536
  int*   bsum   = (int*)(ws + 10865536);          // 1,024
  int*   bbase  = (int*)(ws + 10866560);          // 1,024
  u16*   Wbf    = (u16*)(ws + 10867584);          // 32,768
  u16*   Wrbf   = (u16*)(ws + 10900352);          // 32,768
  float* scale  = (float*)(ws + 10933120);        // 1,024
  float* shift  = (float*)(ws + 10934144);        // 1,024
  u16*   gT   = (u16*)(ws + 10935168);            // 128,000,000
  u16*   xaT  = (u16*)(ws + 138935168);           //  51,200,000
  u16*   xbT  = (u16*)(ws + 190135168);           //  76,800,000 -> ends 266,935,168
  const bool xt = ws_size >= 266935168ull;        // bf16 tier

  hipMemsetAsync(cnt, 0, 2000000, stream);
  hipMemsetAsync(stats, 0, 65536, stream);

  if (xt) {
    k_setup<<<4672, 256, 0, stream>>>(xa, xb, xaT, xbT, ab, ba, cnt, W, Wr, Wbf, Wrbf);
  } else {
    k_prep<<<64, 256, 0, stream>>>(W, Wr, Wbf, Wrbf);
    k_hist<<<2048, 256, 0, stream>>>(ab, ba, cnt);
  }
  k_scanA<<<NSBLK, 256, 0, stream>>>(cnt, bsum);
  k_scanB<<<1, 256, 0, stream>>>(bsum, bbase);
  k_scanC<<<NSBLK, 256, 0, stream>>>(cnt, bbase, off, cursor);
  k_fill<<<2048, 256, 0, stream>>>(ab, ba, cursor, sorted);

  if (xt) {
    k_fuse<<<2048, 256, 0, stream>>>(xaT, xbT, sorted, off, cnt, gT,
                                     Wbf, Wrbf, b, br, stats);
    k_stats<<<1, 256, 0, stream>>>(stats, ga, bea, gb, beb, scale, shift);
    k_norm<1><<<4096, 256, 0, stream>>>(out, gT, scale, shift);
  } else {
    k_gather_f<<<8192, 256, 0, stream>>>(xa, xb, sorted, off, cnt, out);
    k_gemm0<<<2048, 256, 0, stream>>>(xa, xb, out, cnt, Wbf, Wrbf, b, br, stats);
    k_stats<<<1, 256, 0, stream>>>(stats, ga, bea, gb, beb, scale, shift);
    k_norm<0><<<8192, 256, 0, stream>>>(out, gT, scale, shift);
  }
}